// Round 1
// baseline (599.323 us; speedup 1.0000x reference)
//
#include <hip/hip_runtime.h>
#include <hip/hip_bf16.h>
#include <math.h>

#define N_NODES 50000
#define N_EDGES 625000
#define HID 128
#define N_GRAPHS 1000
#define N_FEATS 9
#define VOCAB 119
#define NPAD 50048   // 64*782, multiple of GEMM row tile

// ---------------- degree count ----------------
__global__ __launch_bounds__(256) void count_k(const int* __restrict__ col,
                                               int* __restrict__ deg) {
    int e = blockIdx.x * 256 + threadIdx.x;
    if (e >= N_EDGES) return;
    atomicAdd(&deg[col[e]], 1);
}

// ---------------- dinv = rsqrt(deg+1) ----------------
__global__ __launch_bounds__(256) void dinv_k(const int* __restrict__ deg,
                                              float* __restrict__ dinv) {
    int i = blockIdx.x * 256 + threadIdx.x;
    if (i >= N_NODES) return;
    dinv[i] = rsqrtf((float)(deg[i] + 1));  // +1 self loop; always > 0
}

// ---------------- exclusive scan (single block) ----------------
__global__ __launch_bounds__(1024) void scan_k(const int* __restrict__ cnt,
                                               int* __restrict__ offs) {
    __shared__ int sh[1024];
    int running = 0;
    for (int base = 0; base < N_NODES; base += 1024) {
        int i = base + (int)threadIdx.x;
        int v = (i < N_NODES) ? cnt[i] : 0;
        sh[threadIdx.x] = v;
        __syncthreads();
        for (int o = 1; o < 1024; o <<= 1) {
            int t = (threadIdx.x >= o) ? sh[threadIdx.x - o] : 0;
            __syncthreads();
            sh[threadIdx.x] += t;
            __syncthreads();
        }
        if (i < N_NODES) offs[i] = running + sh[threadIdx.x] - v;
        running += sh[1023];
        __syncthreads();
    }
    if (threadIdx.x == 0) offs[N_NODES] = running;
}

// ---------------- CSR fill ----------------
__global__ __launch_bounds__(256) void fill_k(const int* __restrict__ row,
                                              const int* __restrict__ col,
                                              const int* __restrict__ offs,
                                              int* __restrict__ cursor,
                                              const float* __restrict__ dinv,
                                              int* __restrict__ csrc,
                                              float* __restrict__ cw) {
    int e = blockIdx.x * 256 + threadIdx.x;
    if (e >= N_EDGES) return;
    int c = col[e];
    int r = row[e];
    int pos = offs[c] + atomicAdd(&cursor[c], 1);
    csrc[pos] = r;
    cw[pos] = dinv[r];
}

// ---------------- atom encoder: h[n][d] = sum_f emb[f, x[n,f], d] ----------------
__global__ __launch_bounds__(256) void atom_k(const int* __restrict__ x,
                                              const float* __restrict__ emb,
                                              float* __restrict__ h) {
    int gid = blockIdx.x * 256 + threadIdx.x;   // N*32 threads
    int node = gid >> 5;
    int d4 = (gid & 31) * 4;
    if (node >= N_NODES) return;
    float4 acc = make_float4(0.f, 0.f, 0.f, 0.f);
#pragma unroll
    for (int f = 0; f < N_FEATS; f++) {
        int idx = x[node * N_FEATS + f];
        const float4 v = *(const float4*)(emb + ((size_t)(f * VOCAB + idx)) * HID + d4);
        acc.x += v.x; acc.y += v.y; acc.z += v.z; acc.w += v.w;
    }
    *(float4*)(h + (size_t)node * HID + d4) = acc;
}

// ---------------- GEMM: B = A @ W  (A: NPAD x 128, W: 128 x 128) ----------------
__global__ __launch_bounds__(256) void gemm_k(const float* __restrict__ A,
                                              const float* __restrict__ W,
                                              float* __restrict__ B) {
    __shared__ float sh[64 * 128];          // 32 KiB h-tile
    int block_row = blockIdx.x * 64;
    const float4* A4 = (const float4*)(A + (size_t)block_row * HID);
    float4* sh4 = (float4*)sh;
#pragma unroll
    for (int i = 0; i < 8; i++) {
        int idx = threadIdx.x + i * 256;    // 2048 float4 = 64x128 floats
        sh4[idx] = A4[idx];
    }
    __syncthreads();
    int c = (threadIdx.x & 31) * 4;         // 4 contiguous output cols
    int r0 = threadIdx.x >> 5;              // 0..7, rows r0, r0+8, ..., r0+56
    float4 acc[8];
#pragma unroll
    for (int i = 0; i < 8; i++) acc[i] = make_float4(0.f, 0.f, 0.f, 0.f);
    for (int k = 0; k < 128; k++) {
        float4 w = *(const float4*)(W + k * 128 + c);
#pragma unroll
        for (int i = 0; i < 8; i++) {
            float a = sh[(r0 + i * 8) * 128 + k];
            acc[i].x = fmaf(a, w.x, acc[i].x);
            acc[i].y = fmaf(a, w.y, acc[i].y);
            acc[i].z = fmaf(a, w.z, acc[i].z);
            acc[i].w = fmaf(a, w.w, acc[i].w);
        }
    }
#pragma unroll
    for (int i = 0; i < 8; i++) {
        *(float4*)(B + (size_t)(block_row + r0 + i * 8) * HID + c) = acc[i];
    }
}

// ---------------- aggregation: out[i] = dinv[i]*sum_e w_e*hw[src_e] + dinv[i]^2*hw[i] + b ----------------
__global__ __launch_bounds__(256) void agg_k(const float* __restrict__ hw,
                                             const int* __restrict__ offs,
                                             const int* __restrict__ csrc,
                                             const float* __restrict__ cw,
                                             const float* __restrict__ dinv,
                                             const float* __restrict__ bias,
                                             float* __restrict__ out,
                                             int relu) {
    int wave = (blockIdx.x * 256 + threadIdx.x) >> 6;   // one wave per node
    int lane = threadIdx.x & 63;
    if (wave >= N_NODES) return;
    int node = wave;
    int s = offs[node], e = offs[node + 1];
    int d2 = lane * 2;
    float ax = 0.f, ay = 0.f;
    for (int i = s; i < e; i++) {
        int r = csrc[i];
        float w = cw[i];
        float2 v = *(const float2*)(hw + (size_t)r * HID + d2);
        ax = fmaf(w, v.x, ax);
        ay = fmaf(w, v.y, ay);
    }
    float di = dinv[node];
    float2 self = *(const float2*)(hw + (size_t)node * HID + d2);
    float2 b2v = *(const float2*)(bias + d2);
    float ox = di * ax + di * di * self.x + b2v.x;
    float oy = di * ay + di * di * self.y + b2v.y;
    if (relu) { ox = fmaxf(ox, 0.f); oy = fmaxf(oy, 0.f); }
    float2 o = make_float2(ox, oy);
    *(float2*)(out + (size_t)node * HID + d2) = o;
}

// ---------------- pooling ----------------
__global__ __launch_bounds__(256) void pool_cnt_k(const int* __restrict__ batch,
                                                  int* __restrict__ cnt) {
    int i = blockIdx.x * 256 + threadIdx.x;
    if (i >= N_NODES) return;
    atomicAdd(&cnt[batch[i]], 1);
}

__global__ __launch_bounds__(256) void pool_sum_k(const float* __restrict__ h,
                                                  const int* __restrict__ batch,
                                                  float* __restrict__ pool) {
    int gid = blockIdx.x * 256 + threadIdx.x;   // N*32 threads
    int node = gid >> 5;
    int d4 = (gid & 31) * 4;
    if (node >= N_NODES) return;
    int g = batch[node];
    float4 v = *(const float4*)(h + (size_t)node * HID + d4);
    atomicAdd(&pool[g * HID + d4 + 0], v.x);
    atomicAdd(&pool[g * HID + d4 + 1], v.y);
    atomicAdd(&pool[g * HID + d4 + 2], v.z);
    atomicAdd(&pool[g * HID + d4 + 3], v.w);
}

// ---------------- final: mean, dot lin_w, sigmoid ----------------
__global__ __launch_bounds__(256) void final_k(const float* __restrict__ pool,
                                               const int* __restrict__ cnt,
                                               const float* __restrict__ lin_w,
                                               const float* __restrict__ lin_b,
                                               float* __restrict__ out) {
    int wave = (blockIdx.x * 256 + threadIdx.x) >> 6;   // one wave per graph
    int lane = threadIdx.x & 63;
    if (wave >= N_GRAPHS) return;
    float c = fmaxf((float)cnt[wave], 1.0f);
    int d2 = lane * 2;
    float2 p = *(const float2*)(pool + (size_t)wave * HID + d2);
    float2 w = *(const float2*)(lin_w + d2);
    float s = (p.x * w.x + p.y * w.y) / c;
#pragma unroll
    for (int o = 32; o >= 1; o >>= 1) s += __shfl_xor(s, o, 64);
    if (lane == 0) out[wave] = 1.0f / (1.0f + expf(-(s + lin_b[0])));
}

extern "C" void kernel_launch(void* const* d_in, const int* in_sizes, int n_in,
                              void* d_out, int out_size, void* d_ws, size_t ws_size,
                              hipStream_t stream) {
    const int* x      = (const int*)d_in[0];
    const int* ei     = (const int*)d_in[1];
    const int* batch  = (const int*)d_in[2];
    const float* emb  = (const float*)d_in[3];
    const float* W1   = (const float*)d_in[4];
    const float* b1   = (const float*)d_in[5];
    const float* W2   = (const float*)d_in[6];
    const float* b2   = (const float*)d_in[7];
    const float* W3   = (const float*)d_in[8];
    const float* b3   = (const float*)d_in[9];
    const float* lw   = (const float*)d_in[10];
    const float* lb   = (const float*)d_in[11];
    float* out = (float*)d_out;

    char* ws = (char*)d_ws;
    size_t off = 0;
    auto alloc = [&](size_t bytes) {
        void* p = ws + off;
        off = (off + bytes + 255) & ~(size_t)255;
        return p;
    };
    int*   deg    = (int*)alloc((size_t)N_NODES * 4);
    int*   cursor = (int*)alloc((size_t)N_NODES * 4);
    float* dinv   = (float*)alloc((size_t)N_NODES * 4);
    int*   offs   = (int*)alloc((size_t)(N_NODES + 1) * 4);
    int*   csrc   = (int*)alloc((size_t)N_EDGES * 4);
    float* cw     = (float*)alloc((size_t)N_EDGES * 4);
    float* bufA   = (float*)alloc((size_t)NPAD * HID * 4);
    float* bufB   = (float*)alloc((size_t)NPAD * HID * 4);
    float* pool   = (float*)alloc((size_t)N_GRAPHS * HID * 4);
    int*   cnt    = (int*)alloc((size_t)N_GRAPHS * 4);

    const int* row = ei;
    const int* col = ei + N_EDGES;

    hipMemsetAsync(deg, 0, (size_t)N_NODES * 4, stream);
    hipMemsetAsync(cursor, 0, (size_t)N_NODES * 4, stream);
    hipMemsetAsync(pool, 0, (size_t)N_GRAPHS * HID * 4, stream);
    hipMemsetAsync(cnt, 0, (size_t)N_GRAPHS * 4, stream);

    count_k<<<(N_EDGES + 255) / 256, 256, 0, stream>>>(col, deg);
    dinv_k<<<(N_NODES + 255) / 256, 256, 0, stream>>>(deg, dinv);
    scan_k<<<1, 1024, 0, stream>>>(deg, offs);
    fill_k<<<(N_EDGES + 255) / 256, 256, 0, stream>>>(row, col, offs, cursor, dinv, csrc, cw);
    atom_k<<<(N_NODES * 32 + 255) / 256, 256, 0, stream>>>(x, emb, bufA);

    // layer 1
    gemm_k<<<NPAD / 64, 256, 0, stream>>>(bufA, W1, bufB);
    agg_k<<<(N_NODES * 64) / 256, 256, 0, stream>>>(bufB, offs, csrc, cw, dinv, b1, bufA, 1);
    // layer 2
    gemm_k<<<NPAD / 64, 256, 0, stream>>>(bufA, W2, bufB);
    agg_k<<<(N_NODES * 64) / 256, 256, 0, stream>>>(bufB, offs, csrc, cw, dinv, b2, bufA, 1);
    // layer 3
    gemm_k<<<NPAD / 64, 256, 0, stream>>>(bufA, W3, bufB);
    agg_k<<<(N_NODES * 64) / 256, 256, 0, stream>>>(bufB, offs, csrc, cw, dinv, b3, bufA, 0);

    // pooling + head
    pool_cnt_k<<<(N_NODES + 255) / 256, 256, 0, stream>>>(batch, cnt);
    pool_sum_k<<<(N_NODES * 32 + 255) / 256, 256, 0, stream>>>(bufA, batch, pool);
    final_k<<<(N_GRAPHS * 64) / 256, 256, 0, stream>>>(pool, cnt, lw, lb, out);
}

// Round 2
// 418.580 us; speedup vs baseline: 1.4318x; 1.4318x over previous
//
#include <hip/hip_runtime.h>
#include <hip/hip_bf16.h>
#include <math.h>

#define N_NODES 50000
#define N_EDGES 625000
#define HID 128
#define N_GRAPHS 1000
#define N_FEATS 9
#define VOCAB 119
#define NPAD 50048          // 64*782, multiple of GEMM row tile
#define NB_SCAN ((N_NODES + 255) / 256)   // 196 scan blocks

// ---------------- degree count ----------------
__global__ __launch_bounds__(256) void count_k(const int* __restrict__ col,
                                               int* __restrict__ deg) {
    int e = blockIdx.x * 256 + threadIdx.x;
    if (e >= N_EDGES) return;
    atomicAdd(&deg[col[e]], 1);
}

// ---------------- dinv = rsqrt(deg+1) ----------------
__global__ __launch_bounds__(256) void dinv_k(const int* __restrict__ deg,
                                              float* __restrict__ dinv) {
    int i = blockIdx.x * 256 + threadIdx.x;
    if (i >= N_NODES) return;
    dinv[i] = rsqrtf((float)(deg[i] + 1));  // +1 self loop; always > 0
}

// ---------------- hierarchical exclusive scan over deg -> offs ----------------
__global__ __launch_bounds__(256) void scan1_k(const int* __restrict__ deg,
                                               int* __restrict__ offs,
                                               int* __restrict__ bsum) {
    __shared__ int sh[256];
    int i = blockIdx.x * 256 + threadIdx.x;
    int v = (i < N_NODES) ? deg[i] : 0;
    sh[threadIdx.x] = v;
    __syncthreads();
#pragma unroll
    for (int o = 1; o < 256; o <<= 1) {
        int t = (threadIdx.x >= o) ? sh[threadIdx.x - o] : 0;
        __syncthreads();
        sh[threadIdx.x] += t;
        __syncthreads();
    }
    if (i < N_NODES) offs[i] = sh[threadIdx.x] - v;   // exclusive within block
    if (threadIdx.x == 255) bsum[blockIdx.x] = sh[255];
}

__global__ __launch_bounds__(256) void scan2_k(int* __restrict__ bsum,
                                               int* __restrict__ offs) {
    __shared__ int sh[256];
    int v = (threadIdx.x < NB_SCAN) ? bsum[threadIdx.x] : 0;
    sh[threadIdx.x] = v;
    __syncthreads();
#pragma unroll
    for (int o = 1; o < 256; o <<= 1) {
        int t = (threadIdx.x >= o) ? sh[threadIdx.x - o] : 0;
        __syncthreads();
        sh[threadIdx.x] += t;
        __syncthreads();
    }
    if (threadIdx.x < NB_SCAN) bsum[threadIdx.x] = sh[threadIdx.x] - v;  // exclusive
    if (threadIdx.x == 255) offs[N_NODES] = sh[255];
}

__global__ __launch_bounds__(256) void scan3_k(int* __restrict__ offs,
                                               const int* __restrict__ bsum) {
    int i = blockIdx.x * 256 + threadIdx.x;
    if (i >= N_NODES) return;
    offs[i] += bsum[blockIdx.x];
}

// ---------------- CSR fill ----------------
__global__ __launch_bounds__(256) void fill_k(const int* __restrict__ row,
                                              const int* __restrict__ col,
                                              const int* __restrict__ offs,
                                              int* __restrict__ cursor,
                                              const float* __restrict__ dinv,
                                              int* __restrict__ csrc,
                                              float* __restrict__ cw) {
    int e = blockIdx.x * 256 + threadIdx.x;
    if (e >= N_EDGES) return;
    int c = col[e];
    int r = row[e];
    int pos = offs[c] + atomicAdd(&cursor[c], 1);
    csrc[pos] = r;
    cw[pos] = dinv[r];
}

// ---------------- atom encoder: h[n][d] = sum_f emb[f, x[n,f], d] ----------------
__global__ __launch_bounds__(256) void atom_k(const int* __restrict__ x,
                                              const float* __restrict__ emb,
                                              float* __restrict__ h) {
    int gid = blockIdx.x * 256 + threadIdx.x;   // N*32 threads
    int node = gid >> 5;
    int d4 = (gid & 31) * 4;
    if (node >= N_NODES) return;
    float4 acc = make_float4(0.f, 0.f, 0.f, 0.f);
#pragma unroll
    for (int f = 0; f < N_FEATS; f++) {
        int idx = x[node * N_FEATS + f];
        const float4 v = *(const float4*)(emb + ((size_t)(f * VOCAB + idx)) * HID + d4);
        acc.x += v.x; acc.y += v.y; acc.z += v.z; acc.w += v.w;
    }
    *(float4*)(h + (size_t)node * HID + d4) = acc;
}

// ---------------- GEMM: B = A @ W  (A: NPAD x 128, W: 128 x 128) ----------------
__global__ __launch_bounds__(256) void gemm_k(const float* __restrict__ A,
                                              const float* __restrict__ W,
                                              float* __restrict__ B) {
    __shared__ float sh[64 * 128];          // 32 KiB h-tile
    int block_row = blockIdx.x * 64;
    const float4* A4 = (const float4*)(A + (size_t)block_row * HID);
    float4* sh4 = (float4*)sh;
#pragma unroll
    for (int i = 0; i < 8; i++) {
        int idx = threadIdx.x + i * 256;    // 2048 float4 = 64x128 floats
        sh4[idx] = A4[idx];
    }
    __syncthreads();
    int c = (threadIdx.x & 31) * 4;         // 4 contiguous output cols
    int r0 = threadIdx.x >> 5;              // 0..7, rows r0, r0+8, ..., r0+56
    float4 acc[8];
#pragma unroll
    for (int i = 0; i < 8; i++) acc[i] = make_float4(0.f, 0.f, 0.f, 0.f);
    for (int k = 0; k < 128; k++) {
        float4 w = *(const float4*)(W + k * 128 + c);
#pragma unroll
        for (int i = 0; i < 8; i++) {
            float a = sh[(r0 + i * 8) * 128 + k];
            acc[i].x = fmaf(a, w.x, acc[i].x);
            acc[i].y = fmaf(a, w.y, acc[i].y);
            acc[i].z = fmaf(a, w.z, acc[i].z);
            acc[i].w = fmaf(a, w.w, acc[i].w);
        }
    }
#pragma unroll
    for (int i = 0; i < 8; i++) {
        *(float4*)(B + (size_t)(block_row + r0 + i * 8) * HID + c) = acc[i];
    }
}

// ---------------- aggregation (layers 1,2): out = relu(D^-1/2 A D^-1/2 hw + b) ----------------
__global__ __launch_bounds__(256) void agg_k(const float* __restrict__ hw,
                                             const int* __restrict__ offs,
                                             const int* __restrict__ csrc,
                                             const float* __restrict__ cw,
                                             const float* __restrict__ dinv,
                                             const float* __restrict__ bias,
                                             float* __restrict__ out) {
    int wave = (blockIdx.x * 256 + threadIdx.x) >> 6;   // one wave per node
    int lane = threadIdx.x & 63;
    if (wave >= N_NODES) return;
    int node = wave;
    int s = offs[node], e = offs[node + 1];
    int d2 = lane * 2;
    float ax = 0.f, ay = 0.f;
    for (int i = s; i < e; i++) {
        int r = csrc[i];
        float w = cw[i];
        float2 v = *(const float2*)(hw + (size_t)r * HID + d2);
        ax = fmaf(w, v.x, ax);
        ay = fmaf(w, v.y, ay);
    }
    float di = dinv[node];
    float2 self = *(const float2*)(hw + (size_t)node * HID + d2);
    float2 b2v = *(const float2*)(bias + d2);
    float ox = fmaxf(di * ax + di * di * self.x + b2v.x, 0.f);
    float oy = fmaxf(di * ay + di * di * self.y + b2v.y, 0.f);
    *(float2*)(out + (size_t)node * HID + d2) = make_float2(ox, oy);
}

// ---------------- layer-3 aggregation fused with dot(lin_w): nodeval[n] = h3[n]·lin_w ----------------
__global__ __launch_bounds__(256) void agg3_k(const float* __restrict__ hw,
                                              const int* __restrict__ offs,
                                              const int* __restrict__ csrc,
                                              const float* __restrict__ cw,
                                              const float* __restrict__ dinv,
                                              const float* __restrict__ bias,
                                              const float* __restrict__ lin_w,
                                              float* __restrict__ nodeval) {
    int wave = (blockIdx.x * 256 + threadIdx.x) >> 6;   // one wave per node
    int lane = threadIdx.x & 63;
    if (wave >= N_NODES) return;
    int node = wave;
    int s = offs[node], e = offs[node + 1];
    int d2 = lane * 2;
    float ax = 0.f, ay = 0.f;
    for (int i = s; i < e; i++) {
        int r = csrc[i];
        float w = cw[i];
        float2 v = *(const float2*)(hw + (size_t)r * HID + d2);
        ax = fmaf(w, v.x, ax);
        ay = fmaf(w, v.y, ay);
    }
    float di = dinv[node];
    float2 self = *(const float2*)(hw + (size_t)node * HID + d2);
    float2 b2v = *(const float2*)(bias + d2);
    float ox = di * ax + di * di * self.x + b2v.x;
    float oy = di * ay + di * di * self.y + b2v.y;
    float2 lw2 = *(const float2*)(lin_w + d2);
    float sdot = ox * lw2.x + oy * lw2.y;
#pragma unroll
    for (int o = 32; o >= 1; o >>= 1) sdot += __shfl_xor(sdot, o, 64);
    if (lane == 0) nodeval[node] = sdot;
}

// ---------------- per-graph node histogram (sorted batch) ----------------
__global__ __launch_bounds__(256) void pool_cnt_k(const int* __restrict__ batch,
                                                  int* __restrict__ cnt) {
    int i = blockIdx.x * 256 + threadIdx.x;
    if (i >= N_NODES) return;
    atomicAdd(&cnt[batch[i]], 1);
}

// ---------------- exclusive scan of cnt (G=1000 <= 1024) -> goff ----------------
__global__ __launch_bounds__(1024) void gscan_k(const int* __restrict__ cnt,
                                                int* __restrict__ goff) {
    __shared__ int sh[1024];
    int v = (threadIdx.x < N_GRAPHS) ? cnt[threadIdx.x] : 0;
    sh[threadIdx.x] = v;
    __syncthreads();
#pragma unroll
    for (int o = 1; o < 1024; o <<= 1) {
        int t = (threadIdx.x >= o) ? sh[threadIdx.x - o] : 0;
        __syncthreads();
        sh[threadIdx.x] += t;
        __syncthreads();
    }
    if (threadIdx.x < N_GRAPHS) goff[threadIdx.x] = sh[threadIdx.x] - v;
    if (threadIdx.x == 1023) goff[N_GRAPHS] = sh[1023];
}

// ---------------- segmented mean + sigmoid: out[g] ----------------
__global__ __launch_bounds__(256) void graph_out_k(const float* __restrict__ nodeval,
                                                   const int* __restrict__ goff,
                                                   const float* __restrict__ lin_b,
                                                   float* __restrict__ out) {
    int wave = (blockIdx.x * 256 + threadIdx.x) >> 6;   // one wave per graph
    int lane = threadIdx.x & 63;
    if (wave >= N_GRAPHS) return;
    int s0 = goff[wave], s1 = goff[wave + 1];
    float s = 0.f;
    for (int j = s0 + lane; j < s1; j += 64) s += nodeval[j];
#pragma unroll
    for (int o = 32; o >= 1; o >>= 1) s += __shfl_xor(s, o, 64);
    if (lane == 0) {
        float c = fmaxf((float)(s1 - s0), 1.0f);
        out[wave] = 1.0f / (1.0f + expf(-(s / c + lin_b[0])));
    }
}

extern "C" void kernel_launch(void* const* d_in, const int* in_sizes, int n_in,
                              void* d_out, int out_size, void* d_ws, size_t ws_size,
                              hipStream_t stream) {
    const int* x      = (const int*)d_in[0];
    const int* ei     = (const int*)d_in[1];
    const int* batch  = (const int*)d_in[2];
    const float* emb  = (const float*)d_in[3];
    const float* W1   = (const float*)d_in[4];
    const float* b1   = (const float*)d_in[5];
    const float* W2   = (const float*)d_in[6];
    const float* b2   = (const float*)d_in[7];
    const float* W3   = (const float*)d_in[8];
    const float* b3   = (const float*)d_in[9];
    const float* lw   = (const float*)d_in[10];
    const float* lb   = (const float*)d_in[11];
    float* out = (float*)d_out;

    char* ws = (char*)d_ws;
    size_t off = 0;
    auto alloc = [&](size_t bytes) {
        void* p = ws + off;
        off = (off + bytes + 255) & ~(size_t)255;
        return p;
    };
    int*   deg    = (int*)alloc((size_t)N_NODES * 4);
    int*   cursor = (int*)alloc((size_t)N_NODES * 4);
    float* dinv   = (float*)alloc((size_t)N_NODES * 4);
    int*   offs   = (int*)alloc((size_t)(N_NODES + 1) * 4);
    int*   bsum   = (int*)alloc((size_t)NB_SCAN * 4);
    int*   csrc   = (int*)alloc((size_t)N_EDGES * 4);
    float* cw     = (float*)alloc((size_t)N_EDGES * 4);
    float* bufA   = (float*)alloc((size_t)NPAD * HID * 4);
    float* bufB   = (float*)alloc((size_t)NPAD * HID * 4);
    float* nodeval= (float*)alloc((size_t)N_NODES * 4);
    int*   cnt    = (int*)alloc((size_t)N_GRAPHS * 4);
    int*   goff   = (int*)alloc((size_t)(N_GRAPHS + 1) * 4);

    const int* row = ei;
    const int* col = ei + N_EDGES;

    hipMemsetAsync(deg, 0, (size_t)N_NODES * 4, stream);
    hipMemsetAsync(cursor, 0, (size_t)N_NODES * 4, stream);
    hipMemsetAsync(cnt, 0, (size_t)N_GRAPHS * 4, stream);

    count_k<<<(N_EDGES + 255) / 256, 256, 0, stream>>>(col, deg);
    dinv_k<<<(N_NODES + 255) / 256, 256, 0, stream>>>(deg, dinv);
    scan1_k<<<NB_SCAN, 256, 0, stream>>>(deg, offs, bsum);
    scan2_k<<<1, 256, 0, stream>>>(bsum, offs);
    scan3_k<<<NB_SCAN, 256, 0, stream>>>(offs, bsum);
    fill_k<<<(N_EDGES + 255) / 256, 256, 0, stream>>>(row, col, offs, cursor, dinv, csrc, cw);
    atom_k<<<(N_NODES * 32 + 255) / 256, 256, 0, stream>>>(x, emb, bufA);

    // layer 1
    gemm_k<<<NPAD / 64, 256, 0, stream>>>(bufA, W1, bufB);
    agg_k<<<(N_NODES * 64) / 256, 256, 0, stream>>>(bufB, offs, csrc, cw, dinv, b1, bufA);
    // layer 2
    gemm_k<<<NPAD / 64, 256, 0, stream>>>(bufA, W2, bufB);
    agg_k<<<(N_NODES * 64) / 256, 256, 0, stream>>>(bufB, offs, csrc, cw, dinv, b2, bufA);
    // layer 3 (fused with lin_w dot)
    gemm_k<<<NPAD / 64, 256, 0, stream>>>(bufA, W3, bufB);
    agg3_k<<<(N_NODES * 64) / 256, 256, 0, stream>>>(bufB, offs, csrc, cw, dinv, b3, lw, nodeval);

    // pooling + head (batch is sorted -> segmented reduction, no atomics)
    pool_cnt_k<<<(N_NODES + 255) / 256, 256, 0, stream>>>(batch, cnt);
    gscan_k<<<1, 1024, 0, stream>>>(cnt, goff);
    graph_out_k<<<(N_GRAPHS * 64 + 255) / 256, 256, 0, stream>>>(nodeval, goff, lb, out);
}

// Round 3
// 302.957 us; speedup vs baseline: 1.9782x; 1.3816x over previous
//
#include <hip/hip_runtime.h>
#include <hip/hip_bf16.h>
#include <math.h>

#define N_NODES 50000
#define N_EDGES 625000
#define HID 128
#define N_GRAPHS 1000
#define N_FEATS 9
#define VOCAB 119
#define NPAD 50048          // 64*782, multiple of GEMM row tile
#define NB_SCAN ((N_NODES + 255) / 256)   // 196 scan blocks

typedef __attribute__((ext_vector_type(8))) short short8;
typedef __attribute__((ext_vector_type(4))) float f32x4;

// ---- bf16 helpers (bit ops; bf16->f32 is a shift, f32->bf16 is RNE) ----
static __device__ __forceinline__ float bflo(unsigned int w) {
    return __uint_as_float(w << 16);
}
static __device__ __forceinline__ float bfhi(unsigned int w) {
    return __uint_as_float(w & 0xffff0000u);
}
static __device__ __forceinline__ unsigned int f2bf(float f) {
    unsigned int u = __float_as_uint(f);
    return (u + 0x7fffu + ((u >> 16) & 1u)) >> 16;   // RNE
}
static __device__ __forceinline__ uint2 pack4(float a, float b, float c, float d) {
    uint2 r;
    r.x = f2bf(a) | (f2bf(b) << 16);
    r.y = f2bf(c) | (f2bf(d) << 16);
    return r;
}

// ---------------- degree count ----------------
__global__ __launch_bounds__(256) void count_k(const int* __restrict__ col,
                                               int* __restrict__ deg) {
    int e = blockIdx.x * 256 + threadIdx.x;
    if (e >= N_EDGES) return;
    atomicAdd(&deg[col[e]], 1);
}

// ---------------- scan pass 1 (also computes dinv) ----------------
__global__ __launch_bounds__(256) void scan1_k(const int* __restrict__ deg,
                                               float* __restrict__ dinv,
                                               int* __restrict__ offs,
                                               int* __restrict__ bsum) {
    __shared__ int sh[256];
    int i = blockIdx.x * 256 + threadIdx.x;
    int v = (i < N_NODES) ? deg[i] : 0;
    if (i < N_NODES) dinv[i] = rsqrtf((float)(v + 1));   // +1 self loop
    sh[threadIdx.x] = v;
    __syncthreads();
#pragma unroll
    for (int o = 1; o < 256; o <<= 1) {
        int t = (threadIdx.x >= o) ? sh[threadIdx.x - o] : 0;
        __syncthreads();
        sh[threadIdx.x] += t;
        __syncthreads();
    }
    if (i < N_NODES) offs[i] = sh[threadIdx.x] - v;
    if (threadIdx.x == 255) bsum[blockIdx.x] = sh[255];
}

__global__ __launch_bounds__(256) void scan2_k(int* __restrict__ bsum,
                                               int* __restrict__ offs) {
    __shared__ int sh[256];
    int v = (threadIdx.x < NB_SCAN) ? bsum[threadIdx.x] : 0;
    sh[threadIdx.x] = v;
    __syncthreads();
#pragma unroll
    for (int o = 1; o < 256; o <<= 1) {
        int t = (threadIdx.x >= o) ? sh[threadIdx.x - o] : 0;
        __syncthreads();
        sh[threadIdx.x] += t;
        __syncthreads();
    }
    if (threadIdx.x < NB_SCAN) bsum[threadIdx.x] = sh[threadIdx.x] - v;
    if (threadIdx.x == 255) offs[N_NODES] = sh[255];
}

__global__ __launch_bounds__(256) void scan3_k(int* __restrict__ offs,
                                               const int* __restrict__ bsum) {
    int i = blockIdx.x * 256 + threadIdx.x;
    if (i >= N_NODES) return;
    offs[i] += bsum[blockIdx.x];
}

// ---------------- CSR fill (indices only; weights folded into GEMM prescale) ----------------
__global__ __launch_bounds__(256) void fill_k(const int* __restrict__ row,
                                              const int* __restrict__ col,
                                              const int* __restrict__ offs,
                                              int* __restrict__ cursor,
                                              int* __restrict__ csrc) {
    int e = blockIdx.x * 256 + threadIdx.x;
    if (e >= N_EDGES) return;
    int c = col[e];
    int pos = offs[c] + atomicAdd(&cursor[c], 1);
    csrc[pos] = row[e];
}

// ---------------- atom encoder -> bf16 h ----------------
__global__ __launch_bounds__(256) void atom_k(const int* __restrict__ x,
                                              const float* __restrict__ emb,
                                              unsigned short* __restrict__ h) {
    int gid = blockIdx.x * 256 + threadIdx.x;   // N*32 threads
    int node = gid >> 5;
    int sub = gid & 31;
    if (node >= N_NODES) return;
    int d4 = sub * 4;
    float4 acc = make_float4(0.f, 0.f, 0.f, 0.f);
#pragma unroll
    for (int f = 0; f < N_FEATS; f++) {
        int idx = x[node * N_FEATS + f];
        const float4 v = *(const float4*)(emb + ((size_t)(f * VOCAB + idx)) * HID + d4);
        acc.x += v.x; acc.y += v.y; acc.z += v.z; acc.w += v.w;
    }
    ((uint2*)h)[(size_t)node * 32 + sub] = pack4(acc.x, acc.y, acc.z, acc.w);
}

// ---------------- W prep: fp32 [k][n] -> bf16 W^T [n][k], all 3 layers ----------------
__global__ __launch_bounds__(256) void wprep_k(const float* __restrict__ W1,
                                               const float* __restrict__ W2,
                                               const float* __restrict__ W3,
                                               unsigned short* __restrict__ Wt) {
    int t = blockIdx.x * 256 + threadIdx.x;     // 3*16384 threads
    int which = t >> 14;
    int rem = t & 16383;
    int n = rem >> 7, k = rem & 127;
    const float* W = (which == 0) ? W1 : (which == 1) ? W2 : W3;
    Wt[which * 16384 + n * 128 + k] = (unsigned short)f2bf(W[k * 128 + n]);
}

// ---------------- GEMM (MFMA bf16): B = dinv[row] * (A @ W), bf16 out ----------------
__global__ __launch_bounds__(256) void gemm_k(const unsigned short* __restrict__ A,   // bf16 [NPAD][128]
                                              const unsigned short* __restrict__ Wt,  // bf16 [128][128] = W^T
                                              const float* __restrict__ dinv,
                                              unsigned short* __restrict__ B) {
    int w = threadIdx.x >> 6;                   // wave 0..3
    int l = threadIdx.x & 63;
    int lm = l & 15, lk = l >> 4;
    int m = blockIdx.x * 64 + w * 16 + lm;      // output row
    f32x4 acc[8];
#pragma unroll
    for (int nt = 0; nt < 8; nt++) acc[nt] = (f32x4)0.f;
    const short8* Arow = (const short8*)(A + (size_t)m * HID);
#pragma unroll
    for (int kk = 0; kk < 4; kk++) {
        short8 af = Arow[kk * 4 + lk];
#pragma unroll
        for (int nt = 0; nt < 8; nt++) {
            short8 bf = ((const short8*)(Wt + (size_t)(nt * 16 + lm) * HID))[kk * 4 + lk];
            // operand swap: D' = (A@W)^T fragment -> each lane holds 4 contiguous out cols
            acc[nt] = __builtin_amdgcn_mfma_f32_16x16x32_bf16(bf, af, acc[nt], 0, 0, 0);
        }
    }
    float di = dinv[m < N_NODES ? m : N_NODES - 1];
#pragma unroll
    for (int nt = 0; nt < 8; nt++) {
        int n0 = nt * 16 + lk * 4;
        uint2 p = pack4(di * acc[nt][0], di * acc[nt][1], di * acc[nt][2], di * acc[nt][3]);
        *(uint2*)(B + (size_t)m * HID + n0) = p;
    }
}

// ---------------- aggregation (layers 1,2): out = relu(dinv*(sum nbrs + self) + b), bf16 ----------------
template <int RELU>
__global__ __launch_bounds__(256) void agg_k(const unsigned short* __restrict__ hwp,  // prescaled bf16
                                             const int* __restrict__ offs,
                                             const int* __restrict__ csrc,
                                             const float* __restrict__ dinv,
                                             const float* __restrict__ bias,
                                             unsigned short* __restrict__ out) {
    int t = blockIdx.x * 256 + threadIdx.x;     // N*32 threads, half-wave per node
    int node = t >> 5;
    if (node >= N_NODES) return;
    int sub = t & 31;
    const uint2* H = (const uint2*)hwp;         // 8B chunks, 32 per row
    int s = offs[node], e = offs[node + 1];
    uint2 v = H[(size_t)node * 32 + sub];       // self term (already dinv[node]-scaled)
    float a0 = bflo(v.x), a1 = bfhi(v.x), a2 = bflo(v.y), a3 = bfhi(v.y);
    for (int i = s; i < e; i++) {
        int r = csrc[i];
        uint2 u = H[(size_t)r * 32 + sub];
        a0 += bflo(u.x); a1 += bfhi(u.x); a2 += bflo(u.y); a3 += bfhi(u.y);
    }
    float di = dinv[node];
    float4 b4 = *(const float4*)(bias + sub * 4);
    a0 = fmaf(di, a0, b4.x);
    a1 = fmaf(di, a1, b4.y);
    a2 = fmaf(di, a2, b4.z);
    a3 = fmaf(di, a3, b4.w);
    if (RELU) {
        a0 = fmaxf(a0, 0.f); a1 = fmaxf(a1, 0.f);
        a2 = fmaxf(a2, 0.f); a3 = fmaxf(a3, 0.f);
    }
    ((uint2*)out)[(size_t)node * 32 + sub] = pack4(a0, a1, a2, a3);
}

// ---------------- layer-3 aggregation fused with dot(lin_w) -> nodeval ----------------
__global__ __launch_bounds__(256) void agg3_k(const unsigned short* __restrict__ hwp,
                                              const int* __restrict__ offs,
                                              const int* __restrict__ csrc,
                                              const float* __restrict__ dinv,
                                              const float* __restrict__ bias,
                                              const float* __restrict__ lin_w,
                                              float* __restrict__ nodeval) {
    int t = blockIdx.x * 256 + threadIdx.x;
    int node = t >> 5;
    if (node >= N_NODES) return;
    int sub = t & 31;
    const uint2* H = (const uint2*)hwp;
    int s = offs[node], e = offs[node + 1];
    uint2 v = H[(size_t)node * 32 + sub];
    float a0 = bflo(v.x), a1 = bfhi(v.x), a2 = bflo(v.y), a3 = bfhi(v.y);
    for (int i = s; i < e; i++) {
        int r = csrc[i];
        uint2 u = H[(size_t)r * 32 + sub];
        a0 += bflo(u.x); a1 += bfhi(u.x); a2 += bflo(u.y); a3 += bfhi(u.y);
    }
    float di = dinv[node];
    float4 b4 = *(const float4*)(bias + sub * 4);
    float4 w4 = *(const float4*)(lin_w + sub * 4);
    float o0 = fmaf(di, a0, b4.x);
    float o1 = fmaf(di, a1, b4.y);
    float o2 = fmaf(di, a2, b4.z);
    float o3 = fmaf(di, a3, b4.w);
    float sdot = o0 * w4.x + o1 * w4.y + o2 * w4.z + o3 * w4.w;
#pragma unroll
    for (int o = 16; o >= 1; o >>= 1) sdot += __shfl_xor(sdot, o, 64);
    if (sub == 0) nodeval[node] = sdot;
}

// ---------------- goff from sorted batch: goff[g] = #{i: batch[i] < g} ----------------
__global__ __launch_bounds__(256) void goff_k(const int* __restrict__ batch,
                                              int* __restrict__ goff) {
    int i = blockIdx.x * 256 + threadIdx.x;
    if (i > N_NODES) return;
    int bprev = (i == 0) ? -1 : batch[i - 1];
    int bcur = (i == N_NODES) ? N_GRAPHS : batch[i];
    for (int g = bprev + 1; g <= bcur; g++) goff[g] = i;
}

// ---------------- segmented mean + sigmoid ----------------
__global__ __launch_bounds__(256) void graph_out_k(const float* __restrict__ nodeval,
                                                   const int* __restrict__ goff,
                                                   const float* __restrict__ lin_b,
                                                   float* __restrict__ out) {
    int wave = (blockIdx.x * 256 + threadIdx.x) >> 6;   // one wave per graph
    int lane = threadIdx.x & 63;
    if (wave >= N_GRAPHS) return;
    int s0 = goff[wave], s1 = goff[wave + 1];
    float s = 0.f;
    for (int j = s0 + lane; j < s1; j += 64) s += nodeval[j];
#pragma unroll
    for (int o = 32; o >= 1; o >>= 1) s += __shfl_xor(s, o, 64);
    if (lane == 0) {
        float c = fmaxf((float)(s1 - s0), 1.0f);
        out[wave] = 1.0f / (1.0f + expf(-(s / c + lin_b[0])));
    }
}

extern "C" void kernel_launch(void* const* d_in, const int* in_sizes, int n_in,
                              void* d_out, int out_size, void* d_ws, size_t ws_size,
                              hipStream_t stream) {
    const int* x      = (const int*)d_in[0];
    const int* ei     = (const int*)d_in[1];
    const int* batch  = (const int*)d_in[2];
    const float* emb  = (const float*)d_in[3];
    const float* W1   = (const float*)d_in[4];
    const float* b1   = (const float*)d_in[5];
    const float* W2   = (const float*)d_in[6];
    const float* b2   = (const float*)d_in[7];
    const float* W3   = (const float*)d_in[8];
    const float* b3   = (const float*)d_in[9];
    const float* lw   = (const float*)d_in[10];
    const float* lb   = (const float*)d_in[11];
    float* out = (float*)d_out;

    char* ws = (char*)d_ws;
    size_t off = 0;
    auto alloc = [&](size_t bytes) {
        void* p = ws + off;
        off = (off + bytes + 255) & ~(size_t)255;
        return p;
    };
    int*   deg     = (int*)alloc((size_t)N_NODES * 4);
    int*   cursor  = (int*)alloc((size_t)N_NODES * 4);
    float* dinv    = (float*)alloc((size_t)N_NODES * 4);
    int*   offs    = (int*)alloc((size_t)(N_NODES + 1) * 4);
    int*   bsum    = (int*)alloc((size_t)NB_SCAN * 4);
    int*   csrc    = (int*)alloc((size_t)N_EDGES * 4);
    unsigned short* bufA = (unsigned short*)alloc((size_t)NPAD * HID * 2);
    unsigned short* bufB = (unsigned short*)alloc((size_t)NPAD * HID * 2);
    unsigned short* Wt   = (unsigned short*)alloc((size_t)3 * HID * HID * 2);
    float* nodeval = (float*)alloc((size_t)N_NODES * 4);
    int*   goff    = (int*)alloc((size_t)(N_GRAPHS + 1) * 4);

    const int* row = ei;
    const int* col = ei + N_EDGES;

    hipMemsetAsync(deg, 0, (size_t)N_NODES * 4, stream);
    hipMemsetAsync(cursor, 0, (size_t)N_NODES * 4, stream);

    count_k<<<(N_EDGES + 255) / 256, 256, 0, stream>>>(col, deg);
    scan1_k<<<NB_SCAN, 256, 0, stream>>>(deg, dinv, offs, bsum);
    scan2_k<<<1, 256, 0, stream>>>(bsum, offs);
    scan3_k<<<NB_SCAN, 256, 0, stream>>>(offs, bsum);
    fill_k<<<(N_EDGES + 255) / 256, 256, 0, stream>>>(row, col, offs, cursor, csrc);
    wprep_k<<<(3 * HID * HID) / 256, 256, 0, stream>>>(W1, W2, W3, Wt);
    atom_k<<<(N_NODES * 32 + 255) / 256, 256, 0, stream>>>(x, emb, bufA);
    goff_k<<<(N_NODES + 1 + 255) / 256, 256, 0, stream>>>(batch, goff);

    // layer 1
    gemm_k<<<NPAD / 64, 256, 0, stream>>>(bufA, Wt, dinv, bufB);
    agg_k<1><<<(N_NODES * 32 + 255) / 256, 256, 0, stream>>>(bufB, offs, csrc, dinv, b1, bufA);
    // layer 2
    gemm_k<<<NPAD / 64, 256, 0, stream>>>(bufA, Wt + 16384, dinv, bufB);
    agg_k<1><<<(N_NODES * 32 + 255) / 256, 256, 0, stream>>>(bufB, offs, csrc, dinv, b2, bufA);
    // layer 3 (fused with lin_w dot)
    gemm_k<<<NPAD / 64, 256, 0, stream>>>(bufA, Wt + 32768, dinv, bufB);
    agg3_k<<<(N_NODES * 32 + 255) / 256, 256, 0, stream>>>(bufB, offs, csrc, dinv, b3, lw, nodeval);

    // pooled head
    graph_out_k<<<(N_GRAPHS * 64 + 255) / 256, 256, 0, stream>>>(nodeval, goff, lb, out);
}

// Round 4
// 248.350 us; speedup vs baseline: 2.4132x; 1.2199x over previous
//
#include <hip/hip_runtime.h>
#include <hip/hip_bf16.h>
#include <math.h>

#define N_NODES 50000
#define N_EDGES 625000
#define HID 128
#define N_GRAPHS 1000
#define N_FEATS 9
#define VOCAB 119
#define NPAD 50048          // 64*782, multiple of GEMM row tile; rows >= N_NODES kept zero
#define SENTINEL N_NODES    // pad gathers hit this all-zero row
#define CSR_CAP (N_EDGES + 3 * N_NODES)   // segments padded to multiple of 4
#define NB_SCAN ((N_NODES + 255) / 256)   // 196 scan blocks

typedef __attribute__((ext_vector_type(8))) short short8;
typedef __attribute__((ext_vector_type(4))) float f32x4;

// ---- bf16 helpers ----
static __device__ __forceinline__ float bflo(unsigned int w) {
    return __uint_as_float(w << 16);
}
static __device__ __forceinline__ float bfhi(unsigned int w) {
    return __uint_as_float(w & 0xffff0000u);
}
static __device__ __forceinline__ unsigned int f2bf(float f) {
    unsigned int u = __float_as_uint(f);
    return (u + 0x7fffu + ((u >> 16) & 1u)) >> 16;   // RNE
}
static __device__ __forceinline__ uint2 pack4(float a, float b, float c, float d) {
    uint2 r;
    r.x = f2bf(a) | (f2bf(b) << 16);
    r.y = f2bf(c) | (f2bf(d) << 16);
    return r;
}

// ---------------- degree count ----------------
__global__ __launch_bounds__(256) void count_k(const int* __restrict__ col,
                                               int* __restrict__ deg) {
    int e = blockIdx.x * 256 + threadIdx.x;
    if (e >= N_EDGES) return;
    atomicAdd(&deg[col[e]], 1);
}

// ---------------- scan pass 1 over round4(deg); also computes dinv ----------------
__global__ __launch_bounds__(256) void scan1_k(const int* __restrict__ deg,
                                               float* __restrict__ dinv,
                                               int* __restrict__ offs,
                                               int* __restrict__ bsum) {
    __shared__ int sh[256];
    int i = blockIdx.x * 256 + threadIdx.x;
    int d = (i < N_NODES) ? deg[i] : 0;
    if (i < N_NODES) dinv[i] = rsqrtf((float)(d + 1));   // +1 self loop
    int v = (d + 3) & ~3;                                // padded segment length
    sh[threadIdx.x] = v;
    __syncthreads();
#pragma unroll
    for (int o = 1; o < 256; o <<= 1) {
        int t = (threadIdx.x >= o) ? sh[threadIdx.x - o] : 0;
        __syncthreads();
        sh[threadIdx.x] += t;
        __syncthreads();
    }
    if (i < N_NODES) offs[i] = sh[threadIdx.x] - v;
    if (threadIdx.x == 255) bsum[blockIdx.x] = sh[255];
}

__global__ __launch_bounds__(256) void scan2_k(int* __restrict__ bsum,
                                               int* __restrict__ offs) {
    __shared__ int sh[256];
    int v = (threadIdx.x < NB_SCAN) ? bsum[threadIdx.x] : 0;
    sh[threadIdx.x] = v;
    __syncthreads();
#pragma unroll
    for (int o = 1; o < 256; o <<= 1) {
        int t = (threadIdx.x >= o) ? sh[threadIdx.x - o] : 0;
        __syncthreads();
        sh[threadIdx.x] += t;
        __syncthreads();
    }
    if (threadIdx.x < NB_SCAN) bsum[threadIdx.x] = sh[threadIdx.x] - v;
    if (threadIdx.x == 255) offs[N_NODES] = sh[255];
}

__global__ __launch_bounds__(256) void scan3_k(int* __restrict__ offs,
                                               const int* __restrict__ bsum) {
    int i = blockIdx.x * 256 + threadIdx.x;
    if (i >= N_NODES) return;
    offs[i] += bsum[blockIdx.x];
}

// ---------------- pad slots [offs+deg, offs+round4(deg)) with sentinel ----------------
__global__ __launch_bounds__(256) void pad_k(const int* __restrict__ deg,
                                             const int* __restrict__ offs,
                                             int* __restrict__ csrc) {
    int i = blockIdx.x * 256 + threadIdx.x;
    if (i >= N_NODES) return;
    int d = deg[i], o = offs[i];
    int r4 = (d + 3) & ~3;
    for (int j = d; j < r4; j++) csrc[o + j] = SENTINEL;
}

// ---------------- CSR fill (indices only) ----------------
__global__ __launch_bounds__(256) void fill_k(const int* __restrict__ row,
                                              const int* __restrict__ col,
                                              const int* __restrict__ offs,
                                              int* __restrict__ cursor,
                                              int* __restrict__ csrc) {
    int e = blockIdx.x * 256 + threadIdx.x;
    if (e >= N_EDGES) return;
    int c = col[e];
    int pos = offs[c] + atomicAdd(&cursor[c], 1);
    csrc[pos] = row[e];
}

// ---------------- atom encoder -> bf16 h ----------------
__global__ __launch_bounds__(256) void atom_k(const int* __restrict__ x,
                                              const float* __restrict__ emb,
                                              unsigned short* __restrict__ h) {
    int gid = blockIdx.x * 256 + threadIdx.x;   // N*32 threads
    int node = gid >> 5;
    int sub = gid & 31;
    if (node >= N_NODES) return;
    int d4 = sub * 4;
    float4 acc = make_float4(0.f, 0.f, 0.f, 0.f);
#pragma unroll
    for (int f = 0; f < N_FEATS; f++) {
        int idx = x[node * N_FEATS + f];
        const float4 v = *(const float4*)(emb + ((size_t)(f * VOCAB + idx)) * HID + d4);
        acc.x += v.x; acc.y += v.y; acc.z += v.z; acc.w += v.w;
    }
    ((uint2*)h)[(size_t)node * 32 + sub] = pack4(acc.x, acc.y, acc.z, acc.w);
}

// ---------------- W prep: fp32 [k][n] -> bf16 W^T [n][k], all 3 layers ----------------
__global__ __launch_bounds__(256) void wprep_k(const float* __restrict__ W1,
                                               const float* __restrict__ W2,
                                               const float* __restrict__ W3,
                                               unsigned short* __restrict__ Wt) {
    int t = blockIdx.x * 256 + threadIdx.x;     // 3*16384 threads
    int which = t >> 14;
    int rem = t & 16383;
    int n = rem >> 7, k = rem & 127;
    const float* W = (which == 0) ? W1 : (which == 1) ? W2 : W3;
    Wt[which * 16384 + n * 128 + k] = (unsigned short)f2bf(W[k * 128 + n]);
}

// ---------------- GEMM (MFMA bf16): B = dinv[row] * (A @ W), bf16 out ----------------
__global__ __launch_bounds__(256) void gemm_k(const unsigned short* __restrict__ A,   // bf16 [NPAD][128]
                                              const unsigned short* __restrict__ Wt,  // bf16 [128][128] = W^T
                                              const float* __restrict__ dinv,
                                              unsigned short* __restrict__ B) {
    int w = threadIdx.x >> 6;                   // wave 0..3
    int l = threadIdx.x & 63;
    int lm = l & 15, lk = l >> 4;
    int m = blockIdx.x * 64 + w * 16 + lm;      // output row
    f32x4 acc[8];
#pragma unroll
    for (int nt = 0; nt < 8; nt++) acc[nt] = (f32x4)0.f;
    const short8* Arow = (const short8*)(A + (size_t)m * HID);
#pragma unroll
    for (int kk = 0; kk < 4; kk++) {
        short8 af = Arow[kk * 4 + lk];
#pragma unroll
        for (int nt = 0; nt < 8; nt++) {
            short8 bf = ((const short8*)(Wt + (size_t)(nt * 16 + lm) * HID))[kk * 4 + lk];
            // operand swap: lane holds 4 contiguous out cols of (A@W)
            acc[nt] = __builtin_amdgcn_mfma_f32_16x16x32_bf16(bf, af, acc[nt], 0, 0, 0);
        }
    }
    float di = (m < N_NODES) ? dinv[m] : 0.f;   // pad rows stay zero
#pragma unroll
    for (int nt = 0; nt < 8; nt++) {
        int n0 = nt * 16 + lk * 4;
        uint2 p = pack4(di * acc[nt][0], di * acc[nt][1], di * acc[nt][2], di * acc[nt][3]);
        *(uint2*)(B + (size_t)m * HID + n0) = p;
    }
}

// ---------------- aggregation: 16 lanes/node, 16B/lane, unroll 4, no tail ----------------
#define AGG_GATHER_BODY                                                         \
    int t = blockIdx.x * 256 + threadIdx.x;                                     \
    int node = t >> 4;                                                          \
    if (node >= N_NODES) return;                                                \
    int sub = t & 15;                                                           \
    const uint4* H = (const uint4*)hwp;                                         \
    int s = offs[node], e = offs[node + 1];                                     \
    uint4 v = H[(size_t)node * 16 + sub];                                       \
    float a0 = bflo(v.x), a1 = bfhi(v.x), a2 = bflo(v.y), a3 = bfhi(v.y);       \
    float a4 = bflo(v.z), a5 = bfhi(v.z), a6 = bflo(v.w), a7 = bfhi(v.w);       \
    for (int i = s; i < e; i += 4) {                                            \
        int4 r = *(const int4*)(csrc + i);                                      \
        uint4 u0 = H[(size_t)r.x * 16 + sub];                                   \
        uint4 u1 = H[(size_t)r.y * 16 + sub];                                   \
        uint4 u2 = H[(size_t)r.z * 16 + sub];                                   \
        uint4 u3 = H[(size_t)r.w * 16 + sub];                                   \
        a0 += bflo(u0.x); a1 += bfhi(u0.x); a2 += bflo(u0.y); a3 += bfhi(u0.y); \
        a4 += bflo(u0.z); a5 += bfhi(u0.z); a6 += bflo(u0.w); a7 += bfhi(u0.w); \
        a0 += bflo(u1.x); a1 += bfhi(u1.x); a2 += bflo(u1.y); a3 += bfhi(u1.y); \
        a4 += bflo(u1.z); a5 += bfhi(u1.z); a6 += bflo(u1.w); a7 += bfhi(u1.w); \
        a0 += bflo(u2.x); a1 += bfhi(u2.x); a2 += bflo(u2.y); a3 += bfhi(u2.y); \
        a4 += bflo(u2.z); a5 += bfhi(u2.z); a6 += bflo(u2.w); a7 += bfhi(u2.w); \
        a0 += bflo(u3.x); a1 += bfhi(u3.x); a2 += bflo(u3.y); a3 += bfhi(u3.y); \
        a4 += bflo(u3.z); a5 += bfhi(u3.z); a6 += bflo(u3.w); a7 += bfhi(u3.w); \
    }                                                                           \
    float di = dinv[node];

// layers 1,2: out = relu(dinv*(sum nbrs + self) + b), bf16
template <int RELU>
__global__ __launch_bounds__(256) void agg_k(const unsigned short* __restrict__ hwp,
                                             const int* __restrict__ offs,
                                             const int* __restrict__ csrc,
                                             const float* __restrict__ dinv,
                                             const float* __restrict__ bias,
                                             unsigned short* __restrict__ out) {
    AGG_GATHER_BODY
    float4 ba = *(const float4*)(bias + sub * 8);
    float4 bb = *(const float4*)(bias + sub * 8 + 4);
    a0 = fmaf(di, a0, ba.x); a1 = fmaf(di, a1, ba.y);
    a2 = fmaf(di, a2, ba.z); a3 = fmaf(di, a3, ba.w);
    a4 = fmaf(di, a4, bb.x); a5 = fmaf(di, a5, bb.y);
    a6 = fmaf(di, a6, bb.z); a7 = fmaf(di, a7, bb.w);
    if (RELU) {
        a0 = fmaxf(a0, 0.f); a1 = fmaxf(a1, 0.f); a2 = fmaxf(a2, 0.f); a3 = fmaxf(a3, 0.f);
        a4 = fmaxf(a4, 0.f); a5 = fmaxf(a5, 0.f); a6 = fmaxf(a6, 0.f); a7 = fmaxf(a7, 0.f);
    }
    uint4 o;
    uint2 p0 = pack4(a0, a1, a2, a3);
    uint2 p1 = pack4(a4, a5, a6, a7);
    o.x = p0.x; o.y = p0.y; o.z = p1.x; o.w = p1.y;
    ((uint4*)out)[(size_t)node * 16 + sub] = o;
}

// layer-3 aggregation fused with dot(lin_w) -> nodeval
__global__ __launch_bounds__(256) void agg3_k(const unsigned short* __restrict__ hwp,
                                              const int* __restrict__ offs,
                                              const int* __restrict__ csrc,
                                              const float* __restrict__ dinv,
                                              const float* __restrict__ bias,
                                              const float* __restrict__ lin_w,
                                              float* __restrict__ nodeval) {
    AGG_GATHER_BODY
    float4 ba = *(const float4*)(bias + sub * 8);
    float4 bb = *(const float4*)(bias + sub * 8 + 4);
    float4 wa = *(const float4*)(lin_w + sub * 8);
    float4 wb = *(const float4*)(lin_w + sub * 8 + 4);
    float sdot = fmaf(di, a0, ba.x) * wa.x + fmaf(di, a1, ba.y) * wa.y
               + fmaf(di, a2, ba.z) * wa.z + fmaf(di, a3, ba.w) * wa.w
               + fmaf(di, a4, bb.x) * wb.x + fmaf(di, a5, bb.y) * wb.y
               + fmaf(di, a6, bb.z) * wb.z + fmaf(di, a7, bb.w) * wb.w;
#pragma unroll
    for (int o = 8; o >= 1; o >>= 1) sdot += __shfl_xor(sdot, o, 64);
    if (sub == 0) nodeval[node] = sdot;
}

// ---------------- goff from sorted batch ----------------
__global__ __launch_bounds__(256) void goff_k(const int* __restrict__ batch,
                                              int* __restrict__ goff) {
    int i = blockIdx.x * 256 + threadIdx.x;
    if (i > N_NODES) return;
    int bprev = (i == 0) ? -1 : batch[i - 1];
    int bcur = (i == N_NODES) ? N_GRAPHS : batch[i];
    for (int g = bprev + 1; g <= bcur; g++) goff[g] = i;
}

// ---------------- segmented mean + sigmoid ----------------
__global__ __launch_bounds__(256) void graph_out_k(const float* __restrict__ nodeval,
                                                   const int* __restrict__ goff,
                                                   const float* __restrict__ lin_b,
                                                   float* __restrict__ out) {
    int wave = (blockIdx.x * 256 + threadIdx.x) >> 6;   // one wave per graph
    int lane = threadIdx.x & 63;
    if (wave >= N_GRAPHS) return;
    int s0 = goff[wave], s1 = goff[wave + 1];
    float s = 0.f;
    for (int j = s0 + lane; j < s1; j += 64) s += nodeval[j];
#pragma unroll
    for (int o = 32; o >= 1; o >>= 1) s += __shfl_xor(s, o, 64);
    if (lane == 0) {
        float c = fmaxf((float)(s1 - s0), 1.0f);
        out[wave] = 1.0f / (1.0f + expf(-(s / c + lin_b[0])));
    }
}

extern "C" void kernel_launch(void* const* d_in, const int* in_sizes, int n_in,
                              void* d_out, int out_size, void* d_ws, size_t ws_size,
                              hipStream_t stream) {
    const int* x      = (const int*)d_in[0];
    const int* ei     = (const int*)d_in[1];
    const int* batch  = (const int*)d_in[2];
    const float* emb  = (const float*)d_in[3];
    const float* W1   = (const float*)d_in[4];
    const float* b1   = (const float*)d_in[5];
    const float* W2   = (const float*)d_in[6];
    const float* b2   = (const float*)d_in[7];
    const float* W3   = (const float*)d_in[8];
    const float* b3   = (const float*)d_in[9];
    const float* lw   = (const float*)d_in[10];
    const float* lb   = (const float*)d_in[11];
    float* out = (float*)d_out;

    char* ws = (char*)d_ws;
    size_t off = 0;
    auto alloc = [&](size_t bytes) {
        void* p = ws + off;
        off = (off + bytes + 255) & ~(size_t)255;
        return p;
    };
    int*   deg     = (int*)alloc((size_t)N_NODES * 4);
    int*   cursor  = (int*)alloc((size_t)N_NODES * 4);
    float* dinv    = (float*)alloc((size_t)N_NODES * 4);
    int*   offs    = (int*)alloc((size_t)(N_NODES + 1) * 4);
    int*   bsum    = (int*)alloc((size_t)NB_SCAN * 4);
    int*   csrc    = (int*)alloc((size_t)CSR_CAP * 4);
    unsigned short* bufA = (unsigned short*)alloc((size_t)NPAD * HID * 2);
    unsigned short* bufB = (unsigned short*)alloc((size_t)NPAD * HID * 2);
    unsigned short* Wt   = (unsigned short*)alloc((size_t)3 * HID * HID * 2);
    float* nodeval = (float*)alloc((size_t)N_NODES * 4);
    int*   goff    = (int*)alloc((size_t)(N_GRAPHS + 1) * 4);

    const int* row = ei;
    const int* col = ei + N_EDGES;

    hipMemsetAsync(deg, 0, (size_t)N_NODES * 4, stream);
    hipMemsetAsync(cursor, 0, (size_t)N_NODES * 4, stream);
    // zero pad rows [N_NODES, NPAD) of bufA so sentinel gathers add 0 through all layers
    hipMemsetAsync(bufA + (size_t)N_NODES * HID, 0,
                   (size_t)(NPAD - N_NODES) * HID * 2, stream);

    count_k<<<(N_EDGES + 255) / 256, 256, 0, stream>>>(col, deg);
    scan1_k<<<NB_SCAN, 256, 0, stream>>>(deg, dinv, offs, bsum);
    scan2_k<<<1, 256, 0, stream>>>(bsum, offs);
    scan3_k<<<NB_SCAN, 256, 0, stream>>>(offs, bsum);
    pad_k<<<(N_NODES + 255) / 256, 256, 0, stream>>>(deg, offs, csrc);
    fill_k<<<(N_EDGES + 255) / 256, 256, 0, stream>>>(row, col, offs, cursor, csrc);
    wprep_k<<<(3 * HID * HID) / 256, 256, 0, stream>>>(W1, W2, W3, Wt);
    atom_k<<<(N_NODES * 32 + 255) / 256, 256, 0, stream>>>(x, emb, bufA);
    goff_k<<<(N_NODES + 1 + 255) / 256, 256, 0, stream>>>(batch, goff);

    // layer 1
    gemm_k<<<NPAD / 64, 256, 0, stream>>>(bufA, Wt, dinv, bufB);
    agg_k<1><<<(N_NODES * 16 + 255) / 256, 256, 0, stream>>>(bufB, offs, csrc, dinv, b1, bufA);
    // layer 2
    gemm_k<<<NPAD / 64, 256, 0, stream>>>(bufA, Wt + 16384, dinv, bufB);
    agg_k<1><<<(N_NODES * 16 + 255) / 256, 256, 0, stream>>>(bufB, offs, csrc, dinv, b2, bufA);
    // layer 3 (fused with lin_w dot)
    gemm_k<<<NPAD / 64, 256, 0, stream>>>(bufA, Wt + 32768, dinv, bufB);
    agg3_k<<<(N_NODES * 16 + 255) / 256, 256, 0, stream>>>(bufB, offs, csrc, dinv, b3, lw, nodeval);

    // pooled head
    graph_out_k<<<(N_GRAPHS * 64 + 255) / 256, 256, 0, stream>>>(nodeval, goff, lb, out);
}

// Round 5
// 244.186 us; speedup vs baseline: 2.4544x; 1.0171x over previous
//
#include <hip/hip_runtime.h>
#include <hip/hip_bf16.h>
#include <math.h>

#define N_NODES 50000
#define N_EDGES 625000
#define HID 128
#define N_GRAPHS 1000
#define N_FEATS 9
#define VOCAB 119
#define NPAD 50048          // 64*782, multiple of GEMM row tile; rows >= N_NODES kept zero
#define SENTINEL N_NODES    // pad gathers hit this all-zero row
#define CSR_CAP (N_EDGES + 3 * N_NODES)   // segments padded to multiple of 4
#define NB_SCAN ((N_NODES + 255) / 256)   // 196 scan blocks

typedef __attribute__((ext_vector_type(8))) short short8;
typedef __attribute__((ext_vector_type(4))) float f32x4;

// ---- bf16 helpers ----
static __device__ __forceinline__ float bflo(unsigned int w) {
    return __uint_as_float(w << 16);
}
static __device__ __forceinline__ float bfhi(unsigned int w) {
    return __uint_as_float(w & 0xffff0000u);
}
static __device__ __forceinline__ unsigned int f2bf(float f) {
    unsigned int u = __float_as_uint(f);
    return (u + 0x7fffu + ((u >> 16) & 1u)) >> 16;   // RNE
}
static __device__ __forceinline__ uint2 pack4(float a, float b, float c, float d) {
    uint2 r;
    r.x = f2bf(a) | (f2bf(b) << 16);
    r.y = f2bf(c) | (f2bf(d) << 16);
    return r;
}

// ---------------- init: replaces hipMemsetAsync (each fill node cost ~45µs!) ----------------
__global__ __launch_bounds__(256) void init_k(int* __restrict__ deg,
                                              int* __restrict__ cursor,
                                              unsigned int* __restrict__ bufA_pad) {
    int i = blockIdx.x * 256 + threadIdx.x;
    if (i < N_NODES) { deg[i] = 0; cursor[i] = 0; }
    // pad rows [N_NODES, NPAD): (NPAD-N_NODES)*HID bf16 = 6144 shorts = 3072 u32
    if (i < (NPAD - N_NODES) * HID / 2) bufA_pad[i] = 0;
}

// ---------------- degree count ----------------
__global__ __launch_bounds__(256) void count_k(const int* __restrict__ col,
                                               int* __restrict__ deg) {
    int e = blockIdx.x * 256 + threadIdx.x;
    if (e >= N_EDGES) return;
    atomicAdd(&deg[col[e]], 1);
}

// ---------------- scan pass 1 over round4(deg); also computes dinv ----------------
__global__ __launch_bounds__(256) void scan1_k(const int* __restrict__ deg,
                                               float* __restrict__ dinv,
                                               int* __restrict__ offs,
                                               int* __restrict__ bsum) {
    __shared__ int sh[256];
    int i = blockIdx.x * 256 + threadIdx.x;
    int d = (i < N_NODES) ? deg[i] : 0;
    if (i < N_NODES) dinv[i] = rsqrtf((float)(d + 1));   // +1 self loop
    int v = (d + 3) & ~3;                                // padded segment length
    sh[threadIdx.x] = v;
    __syncthreads();
#pragma unroll
    for (int o = 1; o < 256; o <<= 1) {
        int t = (threadIdx.x >= o) ? sh[threadIdx.x - o] : 0;
        __syncthreads();
        sh[threadIdx.x] += t;
        __syncthreads();
    }
    if (i < N_NODES) offs[i] = sh[threadIdx.x] - v;
    if (threadIdx.x == 255) bsum[blockIdx.x] = sh[255];
}

__global__ __launch_bounds__(256) void scan2_k(int* __restrict__ bsum,
                                               int* __restrict__ offs) {
    __shared__ int sh[256];
    int v = (threadIdx.x < NB_SCAN) ? bsum[threadIdx.x] : 0;
    sh[threadIdx.x] = v;
    __syncthreads();
#pragma unroll
    for (int o = 1; o < 256; o <<= 1) {
        int t = (threadIdx.x >= o) ? sh[threadIdx.x - o] : 0;
        __syncthreads();
        sh[threadIdx.x] += t;
        __syncthreads();
    }
    if (threadIdx.x < NB_SCAN) bsum[threadIdx.x] = sh[threadIdx.x] - v;
    if (threadIdx.x == 255) offs[N_NODES] = sh[255];
}

__global__ __launch_bounds__(256) void scan3_k(int* __restrict__ offs,
                                               const int* __restrict__ bsum) {
    int i = blockIdx.x * 256 + threadIdx.x;
    if (i >= N_NODES) return;
    offs[i] += bsum[blockIdx.x];
}

// ---------------- pad slots [offs+deg, offs+round4(deg)) with sentinel ----------------
__global__ __launch_bounds__(256) void pad_k(const int* __restrict__ deg,
                                             const int* __restrict__ offs,
                                             int* __restrict__ csrc) {
    int i = blockIdx.x * 256 + threadIdx.x;
    if (i >= N_NODES) return;
    int d = deg[i], o = offs[i];
    int r4 = (d + 3) & ~3;
    for (int j = d; j < r4; j++) csrc[o + j] = SENTINEL;
}

// ---------------- CSR fill (indices only) ----------------
__global__ __launch_bounds__(256) void fill_k(const int* __restrict__ row,
                                              const int* __restrict__ col,
                                              const int* __restrict__ offs,
                                              int* __restrict__ cursor,
                                              int* __restrict__ csrc) {
    int e = blockIdx.x * 256 + threadIdx.x;
    if (e >= N_EDGES) return;
    int c = col[e];
    int pos = offs[c] + atomicAdd(&cursor[c], 1);
    csrc[pos] = row[e];
}

// ---------------- atom encoder -> bf16 h ----------------
__global__ __launch_bounds__(256) void atom_k(const int* __restrict__ x,
                                              const float* __restrict__ emb,
                                              unsigned short* __restrict__ h) {
    int gid = blockIdx.x * 256 + threadIdx.x;   // N*32 threads
    int node = gid >> 5;
    int sub = gid & 31;
    if (node >= N_NODES) return;
    int d4 = sub * 4;
    float4 acc = make_float4(0.f, 0.f, 0.f, 0.f);
#pragma unroll
    for (int f = 0; f < N_FEATS; f++) {
        int idx = x[node * N_FEATS + f];
        const float4 v = *(const float4*)(emb + ((size_t)(f * VOCAB + idx)) * HID + d4);
        acc.x += v.x; acc.y += v.y; acc.z += v.z; acc.w += v.w;
    }
    ((uint2*)h)[(size_t)node * 32 + sub] = pack4(acc.x, acc.y, acc.z, acc.w);
}

// ---------------- W prep: fp32 [k][n] -> bf16 W^T [n][k], all 3 layers ----------------
__global__ __launch_bounds__(256) void wprep_k(const float* __restrict__ W1,
                                               const float* __restrict__ W2,
                                               const float* __restrict__ W3,
                                               unsigned short* __restrict__ Wt) {
    int t = blockIdx.x * 256 + threadIdx.x;     // 3*16384 threads
    int which = t >> 14;
    int rem = t & 16383;
    int n = rem >> 7, k = rem & 127;
    const float* W = (which == 0) ? W1 : (which == 1) ? W2 : W3;
    Wt[which * 16384 + n * 128 + k] = (unsigned short)f2bf(W[k * 128 + n]);
}

// ---------------- GEMM (MFMA bf16): B = dinv[row] * (A @ W), bf16 out ----------------
__global__ __launch_bounds__(256) void gemm_k(const unsigned short* __restrict__ A,   // bf16 [NPAD][128]
                                              const unsigned short* __restrict__ Wt,  // bf16 [128][128] = W^T
                                              const float* __restrict__ dinv,
                                              unsigned short* __restrict__ B) {
    int w = threadIdx.x >> 6;                   // wave 0..3
    int l = threadIdx.x & 63;
    int lm = l & 15, lk = l >> 4;
    int m = blockIdx.x * 64 + w * 16 + lm;      // output row
    f32x4 acc[8];
#pragma unroll
    for (int nt = 0; nt < 8; nt++) acc[nt] = (f32x4)0.f;
    const short8* Arow = (const short8*)(A + (size_t)m * HID);
#pragma unroll
    for (int kk = 0; kk < 4; kk++) {
        short8 af = Arow[kk * 4 + lk];
#pragma unroll
        for (int nt = 0; nt < 8; nt++) {
            short8 bf = ((const short8*)(Wt + (size_t)(nt * 16 + lm) * HID))[kk * 4 + lk];
            // operand swap: lane holds 4 contiguous out cols of (A@W)
            acc[nt] = __builtin_amdgcn_mfma_f32_16x16x32_bf16(bf, af, acc[nt], 0, 0, 0);
        }
    }
    float di = (m < N_NODES) ? dinv[m] : 0.f;   // pad rows stay zero
#pragma unroll
    for (int nt = 0; nt < 8; nt++) {
        int n0 = nt * 16 + lk * 4;
        uint2 p = pack4(di * acc[nt][0], di * acc[nt][1], di * acc[nt][2], di * acc[nt][3]);
        *(uint2*)(B + (size_t)m * HID + n0) = p;
    }
}

// ---------------- aggregation: 16 lanes/node, 16B/lane, unroll 4, no tail ----------------
#define AGG_GATHER_BODY                                                         \
    int t = blockIdx.x * 256 + threadIdx.x;                                     \
    int node = t >> 4;                                                          \
    if (node >= N_NODES) return;                                                \
    int sub = t & 15;                                                           \
    const uint4* H = (const uint4*)hwp;                                         \
    int s = offs[node], e = offs[node + 1];                                     \
    uint4 v = H[(size_t)node * 16 + sub];                                       \
    float a0 = bflo(v.x), a1 = bfhi(v.x), a2 = bflo(v.y), a3 = bfhi(v.y);       \
    float a4 = bflo(v.z), a5 = bfhi(v.z), a6 = bflo(v.w), a7 = bfhi(v.w);       \
    for (int i = s; i < e; i += 4) {                                            \
        int4 r = *(const int4*)(csrc + i);                                      \
        uint4 u0 = H[(size_t)r.x * 16 + sub];                                   \
        uint4 u1 = H[(size_t)r.y * 16 + sub];                                   \
        uint4 u2 = H[(size_t)r.z * 16 + sub];                                   \
        uint4 u3 = H[(size_t)r.w * 16 + sub];                                   \
        a0 += bflo(u0.x); a1 += bfhi(u0.x); a2 += bflo(u0.y); a3 += bfhi(u0.y); \
        a4 += bflo(u0.z); a5 += bfhi(u0.z); a6 += bflo(u0.w); a7 += bfhi(u0.w); \
        a0 += bflo(u1.x); a1 += bfhi(u1.x); a2 += bflo(u1.y); a3 += bfhi(u1.y); \
        a4 += bflo(u1.z); a5 += bfhi(u1.z); a6 += bflo(u1.w); a7 += bfhi(u1.w); \
        a0 += bflo(u2.x); a1 += bfhi(u2.x); a2 += bflo(u2.y); a3 += bfhi(u2.y); \
        a4 += bflo(u2.z); a5 += bfhi(u2.z); a6 += bflo(u2.w); a7 += bfhi(u2.w); \
        a0 += bflo(u3.x); a1 += bfhi(u3.x); a2 += bflo(u3.y); a3 += bfhi(u3.y); \
        a4 += bflo(u3.z); a5 += bfhi(u3.z); a6 += bflo(u3.w); a7 += bfhi(u3.w); \
    }                                                                           \
    float di = dinv[node];

// layers 1,2: out = relu(dinv*(sum nbrs + self) + b), bf16
template <int RELU>
__global__ __launch_bounds__(256) void agg_k(const unsigned short* __restrict__ hwp,
                                             const int* __restrict__ offs,
                                             const int* __restrict__ csrc,
                                             const float* __restrict__ dinv,
                                             const float* __restrict__ bias,
                                             unsigned short* __restrict__ out) {
    AGG_GATHER_BODY
    float4 ba = *(const float4*)(bias + sub * 8);
    float4 bb = *(const float4*)(bias + sub * 8 + 4);
    a0 = fmaf(di, a0, ba.x); a1 = fmaf(di, a1, ba.y);
    a2 = fmaf(di, a2, ba.z); a3 = fmaf(di, a3, ba.w);
    a4 = fmaf(di, a4, bb.x); a5 = fmaf(di, a5, bb.y);
    a6 = fmaf(di, a6, bb.z); a7 = fmaf(di, a7, bb.w);
    if (RELU) {
        a0 = fmaxf(a0, 0.f); a1 = fmaxf(a1, 0.f); a2 = fmaxf(a2, 0.f); a3 = fmaxf(a3, 0.f);
        a4 = fmaxf(a4, 0.f); a5 = fmaxf(a5, 0.f); a6 = fmaxf(a6, 0.f); a7 = fmaxf(a7, 0.f);
    }
    uint4 o;
    uint2 p0 = pack4(a0, a1, a2, a3);
    uint2 p1 = pack4(a4, a5, a6, a7);
    o.x = p0.x; o.y = p0.y; o.z = p1.x; o.w = p1.y;
    ((uint4*)out)[(size_t)node * 16 + sub] = o;
}

// layer-3 aggregation fused with dot(lin_w) -> nodeval
__global__ __launch_bounds__(256) void agg3_k(const unsigned short* __restrict__ hwp,
                                              const int* __restrict__ offs,
                                              const int* __restrict__ csrc,
                                              const float* __restrict__ dinv,
                                              const float* __restrict__ bias,
                                              const float* __restrict__ lin_w,
                                              float* __restrict__ nodeval) {
    AGG_GATHER_BODY
    float4 ba = *(const float4*)(bias + sub * 8);
    float4 bb = *(const float4*)(bias + sub * 8 + 4);
    float4 wa = *(const float4*)(lin_w + sub * 8);
    float4 wb = *(const float4*)(lin_w + sub * 8 + 4);
    float sdot = fmaf(di, a0, ba.x) * wa.x + fmaf(di, a1, ba.y) * wa.y
               + fmaf(di, a2, ba.z) * wa.z + fmaf(di, a3, ba.w) * wa.w
               + fmaf(di, a4, bb.x) * wb.x + fmaf(di, a5, bb.y) * wb.y
               + fmaf(di, a6, bb.z) * wb.z + fmaf(di, a7, bb.w) * wb.w;
#pragma unroll
    for (int o = 8; o >= 1; o >>= 1) sdot += __shfl_xor(sdot, o, 64);
    if (sub == 0) nodeval[node] = sdot;
}

// ---------------- goff from sorted batch ----------------
__global__ __launch_bounds__(256) void goff_k(const int* __restrict__ batch,
                                              int* __restrict__ goff) {
    int i = blockIdx.x * 256 + threadIdx.x;
    if (i > N_NODES) return;
    int bprev = (i == 0) ? -1 : batch[i - 1];
    int bcur = (i == N_NODES) ? N_GRAPHS : batch[i];
    for (int g = bprev + 1; g <= bcur; g++) goff[g] = i;
}

// ---------------- segmented mean + sigmoid ----------------
__global__ __launch_bounds__(256) void graph_out_k(const float* __restrict__ nodeval,
                                                   const int* __restrict__ goff,
                                                   const float* __restrict__ lin_b,
                                                   float* __restrict__ out) {
    int wave = (blockIdx.x * 256 + threadIdx.x) >> 6;   // one wave per graph
    int lane = threadIdx.x & 63;
    if (wave >= N_GRAPHS) return;
    int s0 = goff[wave], s1 = goff[wave + 1];
    float s = 0.f;
    for (int j = s0 + lane; j < s1; j += 64) s += nodeval[j];
#pragma unroll
    for (int o = 32; o >= 1; o >>= 1) s += __shfl_xor(s, o, 64);
    if (lane == 0) {
        float c = fmaxf((float)(s1 - s0), 1.0f);
        out[wave] = 1.0f / (1.0f + expf(-(s / c + lin_b[0])));
    }
}

extern "C" void kernel_launch(void* const* d_in, const int* in_sizes, int n_in,
                              void* d_out, int out_size, void* d_ws, size_t ws_size,
                              hipStream_t stream) {
    const int* x      = (const int*)d_in[0];
    const int* ei     = (const int*)d_in[1];
    const int* batch  = (const int*)d_in[2];
    const float* emb  = (const float*)d_in[3];
    const float* W1   = (const float*)d_in[4];
    const float* b1   = (const float*)d_in[5];
    const float* W2   = (const float*)d_in[6];
    const float* b2   = (const float*)d_in[7];
    const float* W3   = (const float*)d_in[8];
    const float* b3   = (const float*)d_in[9];
    const float* lw   = (const float*)d_in[10];
    const float* lb   = (const float*)d_in[11];
    float* out = (float*)d_out;

    char* ws = (char*)d_ws;
    size_t off = 0;
    auto alloc = [&](size_t bytes) {
        void* p = ws + off;
        off = (off + bytes + 255) & ~(size_t)255;
        return p;
    };
    int*   deg     = (int*)alloc((size_t)N_NODES * 4);
    int*   cursor  = (int*)alloc((size_t)N_NODES * 4);
    float* dinv    = (float*)alloc((size_t)N_NODES * 4);
    int*   offs    = (int*)alloc((size_t)(N_NODES + 1) * 4);
    int*   bsum    = (int*)alloc((size_t)NB_SCAN * 4);
    int*   csrc    = (int*)alloc((size_t)CSR_CAP * 4);
    unsigned short* bufA = (unsigned short*)alloc((size_t)NPAD * HID * 2);
    unsigned short* bufB = (unsigned short*)alloc((size_t)NPAD * HID * 2);
    unsigned short* Wt   = (unsigned short*)alloc((size_t)3 * HID * HID * 2);
    float* nodeval = (float*)alloc((size_t)N_NODES * 4);
    int*   goff    = (int*)alloc((size_t)(N_GRAPHS + 1) * 4);

    const int* row = ei;
    const int* col = ei + N_EDGES;

    // NO hipMemsetAsync: each fill node cost ~45µs in the captured graph.
    init_k<<<NB_SCAN, 256, 0, stream>>>(deg, cursor,
                                        (unsigned int*)(bufA + (size_t)N_NODES * HID));

    count_k<<<(N_EDGES + 255) / 256, 256, 0, stream>>>(col, deg);
    scan1_k<<<NB_SCAN, 256, 0, stream>>>(deg, dinv, offs, bsum);
    scan2_k<<<1, 256, 0, stream>>>(bsum, offs);
    scan3_k<<<NB_SCAN, 256, 0, stream>>>(offs, bsum);
    pad_k<<<(N_NODES + 255) / 256, 256, 0, stream>>>(deg, offs, csrc);
    fill_k<<<(N_EDGES + 255) / 256, 256, 0, stream>>>(row, col, offs, cursor, csrc);
    wprep_k<<<(3 * HID * HID) / 256, 256, 0, stream>>>(W1, W2, W3, Wt);
    atom_k<<<(N_NODES * 32 + 255) / 256, 256, 0, stream>>>(x, emb, bufA);
    goff_k<<<(N_NODES + 1 + 255) / 256, 256, 0, stream>>>(batch, goff);

    // layer 1
    gemm_k<<<NPAD / 64, 256, 0, stream>>>(bufA, Wt, dinv, bufB);
    agg_k<1><<<(N_NODES * 16 + 255) / 256, 256, 0, stream>>>(bufB, offs, csrc, dinv, b1, bufA);
    // layer 2
    gemm_k<<<NPAD / 64, 256, 0, stream>>>(bufA, Wt + 16384, dinv, bufB);
    agg_k<1><<<(N_NODES * 16 + 255) / 256, 256, 0, stream>>>(bufB, offs, csrc, dinv, b2, bufA);
    // layer 3 (fused with lin_w dot)
    gemm_k<<<NPAD / 64, 256, 0, stream>>>(bufA, Wt + 32768, dinv, bufB);
    agg3_k<<<(N_NODES * 16 + 255) / 256, 256, 0, stream>>>(bufB, offs, csrc, dinv, b3, lw, nodeval);

    // pooled head
    graph_out_k<<<(N_GRAPHS * 64 + 255) / 256, 256, 0, stream>>>(nodeval, goff, lb, out);
}

// Round 6
// 191.397 us; speedup vs baseline: 3.1313x; 1.2758x over previous
//
#include <hip/hip_runtime.h>
#include <hip/hip_bf16.h>
#include <math.h>

#define N_NODES 50000
#define N_EDGES 625000
#define HID 128
#define N_GRAPHS 1000
#define N_FEATS 9
#define VOCAB 119
#define NPAD32 50016        // 32*1563: fused-kernel row padding; rows >= N_NODES auto-zeroed
#define SENTINEL N_NODES    // pad gathers hit this all-zero row
#define CSR_CAP (N_EDGES + 3 * N_NODES)   // segments padded to multiple of 4
#define NB_SCAN ((N_NODES + 255) / 256)   // 196 scan blocks
#define LDSW 136            // 128 + 8 pad shorts: keeps 16B align, breaks bank conflicts

typedef __attribute__((ext_vector_type(8))) short short8;
typedef __attribute__((ext_vector_type(4))) float f32x4;

// ---- bf16 helpers ----
static __device__ __forceinline__ float bflo(unsigned int w) {
    return __uint_as_float(w << 16);
}
static __device__ __forceinline__ float bfhi(unsigned int w) {
    return __uint_as_float(w & 0xffff0000u);
}
static __device__ __forceinline__ unsigned int f2bf(float f) {
    unsigned int u = __float_as_uint(f);
    return (u + 0x7fffu + ((u >> 16) & 1u)) >> 16;   // RNE
}
static __device__ __forceinline__ uint2 pack4(float a, float b, float c, float d) {
    uint2 r;
    r.x = f2bf(a) | (f2bf(b) << 16);
    r.y = f2bf(c) | (f2bf(d) << 16);
    return r;
}

// ---------------- init: zero deg/cursor + pad rows of hpA ----------------
__global__ __launch_bounds__(256) void init_k(int* __restrict__ deg,
                                              int* __restrict__ cursor,
                                              unsigned int* __restrict__ hpA_pad) {
    int i = blockIdx.x * 256 + threadIdx.x;
    if (i < N_NODES) { deg[i] = 0; cursor[i] = 0; }
    // rows [N_NODES, NPAD32): 16 rows * 128 bf16 = 1024 u32
    if (i < (NPAD32 - N_NODES) * HID / 2) hpA_pad[i] = 0;
}

// ---------------- degree count ----------------
__global__ __launch_bounds__(256) void count_k(const int* __restrict__ col,
                                               int* __restrict__ deg) {
    int e = blockIdx.x * 256 + threadIdx.x;
    if (e >= N_EDGES) return;
    atomicAdd(&deg[col[e]], 1);
}

// ---------------- scan pass 1 over round4(deg); also computes dinv ----------------
__global__ __launch_bounds__(256) void scan1_k(const int* __restrict__ deg,
                                               float* __restrict__ dinv,
                                               int* __restrict__ offs,
                                               int* __restrict__ bsum) {
    __shared__ int sh[256];
    int i = blockIdx.x * 256 + threadIdx.x;
    int d = (i < N_NODES) ? deg[i] : 0;
    if (i < N_NODES) dinv[i] = rsqrtf((float)(d + 1));   // +1 self loop
    int v = (d + 3) & ~3;                                // padded segment length
    sh[threadIdx.x] = v;
    __syncthreads();
#pragma unroll
    for (int o = 1; o < 256; o <<= 1) {
        int t = (threadIdx.x >= o) ? sh[threadIdx.x - o] : 0;
        __syncthreads();
        sh[threadIdx.x] += t;
        __syncthreads();
    }
    if (i < N_NODES) offs[i] = sh[threadIdx.x] - v;
    if (threadIdx.x == 255) bsum[blockIdx.x] = sh[255];
}

__global__ __launch_bounds__(256) void scan2_k(int* __restrict__ bsum,
                                               int* __restrict__ offs) {
    __shared__ int sh[256];
    int v = (threadIdx.x < NB_SCAN) ? bsum[threadIdx.x] : 0;
    sh[threadIdx.x] = v;
    __syncthreads();
#pragma unroll
    for (int o = 1; o < 256; o <<= 1) {
        int t = (threadIdx.x >= o) ? sh[threadIdx.x - o] : 0;
        __syncthreads();
        sh[threadIdx.x] += t;
        __syncthreads();
    }
    if (threadIdx.x < NB_SCAN) bsum[threadIdx.x] = sh[threadIdx.x] - v;
    if (threadIdx.x == 255) offs[N_NODES] = sh[255];
}

// ---------------- scan3 + sentinel pad, merged (thread-local after bsum add) ----------------
__global__ __launch_bounds__(256) void scan3pad_k(int* __restrict__ offs,
                                                  const int* __restrict__ bsum,
                                                  const int* __restrict__ deg,
                                                  int* __restrict__ csrc) {
    int i = blockIdx.x * 256 + threadIdx.x;
    if (i >= N_NODES) return;
    int o = offs[i] + bsum[blockIdx.x];
    offs[i] = o;
    int d = deg[i];
    int r4 = (d + 3) & ~3;
    for (int j = d; j < r4; j++) csrc[o + j] = SENTINEL;
}

// ---------------- CSR fill (indices only) ----------------
__global__ __launch_bounds__(256) void fill_k(const int* __restrict__ row,
                                              const int* __restrict__ col,
                                              const int* __restrict__ offs,
                                              int* __restrict__ cursor,
                                              int* __restrict__ csrc) {
    int e = blockIdx.x * 256 + threadIdx.x;
    if (e >= N_EDGES) return;
    int c = col[e];
    int pos = offs[c] + atomicAdd(&cursor[c], 1);
    csrc[pos] = row[e];
}

// ---------------- prep: Wt1/Wt2 transpose, w~ = W3@lin_w, cb3 = b3.lin_w, goff ----------------
__global__ __launch_bounds__(256) void prep_k(const float* __restrict__ W1,
                                              const float* __restrict__ W2,
                                              const float* __restrict__ W3,
                                              const float* __restrict__ b3,
                                              const float* __restrict__ lw,
                                              const int* __restrict__ batch,
                                              unsigned short* __restrict__ Wt,
                                              float* __restrict__ wtil,
                                              float* __restrict__ cbuf,
                                              int* __restrict__ goff) {
    int t = blockIdx.x * 256 + threadIdx.x;
    if (t < 32768) {                         // W^T for layers 1,2
        int which = t >> 14;
        int rem = t & 16383;
        int n = rem >> 7, k = rem & 127;
        const float* W = which ? W2 : W1;
        Wt[which * 16384 + n * 128 + k] = (unsigned short)f2bf(W[k * 128 + n]);
    } else if (t < 32896) {                  // w~[k] = sum_n W3[k][n]*lw[n]
        int k = t - 32768;
        float s = 0.f;
        for (int n = 0; n < 128; n++) s += W3[k * 128 + n] * lw[n];
        wtil[k] = s;
    } else if (t == 32896) {                 // cb3 = b3 . lw
        float s = 0.f;
        for (int n = 0; n < 128; n++) s += b3[n] * lw[n];
        cbuf[0] = s;
    } else {                                 // goff from sorted batch
        int i = t - 32897;
        if (i > N_NODES) return;
        int bprev = (i == 0) ? -1 : batch[i - 1];
        int bcur = (i == N_NODES) ? N_GRAPHS : batch[i];
        for (int g = bprev + 1; g <= bcur; g++) goff[g] = i;
    }
}

// ---------------- atom encoder -> prescaled bf16 hp0 = dinv*h0 ----------------
__global__ __launch_bounds__(256) void atom_k(const int* __restrict__ x,
                                              const float* __restrict__ emb,
                                              const float* __restrict__ dinv,
                                              unsigned short* __restrict__ hp) {
    int gid = blockIdx.x * 256 + threadIdx.x;   // N*32 threads
    int node = gid >> 5;
    int sub = gid & 31;
    if (node >= N_NODES) return;
    int d4 = sub * 4;
    float4 acc = make_float4(0.f, 0.f, 0.f, 0.f);
#pragma unroll
    for (int f = 0; f < N_FEATS; f++) {
        int idx = x[node * N_FEATS + f];
        const float4 v = *(const float4*)(emb + ((size_t)(f * VOCAB + idx)) * HID + d4);
        acc.x += v.x; acc.y += v.y; acc.z += v.z; acc.w += v.w;
    }
    float di = dinv[node];
    ((uint2*)hp)[(size_t)node * 32 + sub] =
        pack4(di * acc.x, di * acc.y, di * acc.z, di * acc.w);
}

// ---------------- fused layer: hp_out = dinv * relu( (A^ hp_in) @ W + b ) ----------------
// block = 256 threads = 4 waves, 32 nodes. Phase 1: gather (16 lanes/node, 2 passes)
// into LDS bf16 tile [32][LDSW]. Phase 2: MFMA 32x128 @ 128x128.
__global__ __launch_bounds__(256) void fused_k(const unsigned short* __restrict__ hp_in,
                                               const unsigned short* __restrict__ Wt,
                                               const float* __restrict__ bias,
                                               const float* __restrict__ dinv,
                                               const int* __restrict__ offs,
                                               const int* __restrict__ csrc,
                                               unsigned short* __restrict__ hp_out) {
    __shared__ unsigned short a_sh[32 * LDSW];
    int tid = threadIdx.x;
    int sub = tid & 15, nl = tid >> 4;
    const uint4* H = (const uint4*)hp_in;
#pragma unroll
    for (int n2 = 0; n2 < 2; n2++) {
        int node_local = nl + n2 * 16;
        int node = blockIdx.x * 32 + node_local;
        float a0 = 0.f, a1 = 0.f, a2 = 0.f, a3 = 0.f;
        float a4 = 0.f, a5 = 0.f, a6 = 0.f, a7 = 0.f;
        if (node < N_NODES) {
            int s = offs[node], e = offs[node + 1];
            uint4 v = H[(size_t)node * 16 + sub];     // self (prescaled)
            a0 = bflo(v.x); a1 = bfhi(v.x); a2 = bflo(v.y); a3 = bfhi(v.y);
            a4 = bflo(v.z); a5 = bfhi(v.z); a6 = bflo(v.w); a7 = bfhi(v.w);
            for (int i = s; i < e; i += 4) {
                int4 r = *(const int4*)(csrc + i);
                uint4 u0 = H[(size_t)r.x * 16 + sub];
                uint4 u1 = H[(size_t)r.y * 16 + sub];
                uint4 u2 = H[(size_t)r.z * 16 + sub];
                uint4 u3 = H[(size_t)r.w * 16 + sub];
                a0 += bflo(u0.x); a1 += bfhi(u0.x); a2 += bflo(u0.y); a3 += bfhi(u0.y);
                a4 += bflo(u0.z); a5 += bfhi(u0.z); a6 += bflo(u0.w); a7 += bfhi(u0.w);
                a0 += bflo(u1.x); a1 += bfhi(u1.x); a2 += bflo(u1.y); a3 += bfhi(u1.y);
                a4 += bflo(u1.z); a5 += bfhi(u1.z); a6 += bflo(u1.w); a7 += bfhi(u1.w);
                a0 += bflo(u2.x); a1 += bfhi(u2.x); a2 += bflo(u2.y); a3 += bfhi(u2.y);
                a4 += bflo(u2.z); a5 += bfhi(u2.z); a6 += bflo(u2.w); a7 += bfhi(u2.w);
                a0 += bflo(u3.x); a1 += bfhi(u3.x); a2 += bflo(u3.y); a3 += bfhi(u3.y);
                a4 += bflo(u3.z); a5 += bfhi(u3.z); a6 += bflo(u3.w); a7 += bfhi(u3.w);
            }
            float di = dinv[node];                    // (A^ h)_i = di * (sum + self)
            a0 *= di; a1 *= di; a2 *= di; a3 *= di;
            a4 *= di; a5 *= di; a6 *= di; a7 *= di;
        }
        uint2 p0 = pack4(a0, a1, a2, a3);
        uint2 p1 = pack4(a4, a5, a6, a7);
        uint4 o; o.x = p0.x; o.y = p0.y; o.z = p1.x; o.w = p1.y;
        *(uint4*)(a_sh + node_local * LDSW + sub * 8) = o;
    }
    __syncthreads();
    // MFMA phase: wave w -> rows (w&1)*16..+15, cols (w>>1)*64..+63
    int w = tid >> 6, l = tid & 63;
    int lm = l & 15, lk = l >> 4;
    int rbase = (w & 1) * 16, cbase = (w >> 1) * 64;
    f32x4 acc[4];
#pragma unroll
    for (int nt = 0; nt < 4; nt++) acc[nt] = (f32x4)0.f;
#pragma unroll
    for (int kk = 0; kk < 4; kk++) {
        short8 af = *(const short8*)(a_sh + (rbase + lm) * LDSW + (kk * 4 + lk) * 8);
#pragma unroll
        for (int nt = 0; nt < 4; nt++) {
            short8 bf = *(const short8*)(Wt + (size_t)(cbase + nt * 16 + lm) * HID + (kk * 4 + lk) * 8);
            acc[nt] = __builtin_amdgcn_mfma_f32_16x16x32_bf16(bf, af, acc[nt], 0, 0, 0);
        }
    }
    int m = blockIdx.x * 32 + rbase + lm;
    float di = (m < N_NODES) ? dinv[m] : 0.f;        // pad rows -> 0
#pragma unroll
    for (int nt = 0; nt < 4; nt++) {
        int n0 = cbase + nt * 16 + lk * 4;
        float4 b4 = *(const float4*)(bias + n0);
        float o0 = di * fmaxf(acc[nt][0] + b4.x, 0.f);
        float o1 = di * fmaxf(acc[nt][1] + b4.y, 0.f);
        float o2 = di * fmaxf(acc[nt][2] + b4.z, 0.f);
        float o3 = di * fmaxf(acc[nt][3] + b4.w, 0.f);
        *(uint2*)(hp_out + (size_t)m * HID + n0) = pack4(o0, o1, o2, o3);
    }
}

// ---------------- sp[i] = hp2_i . w~  (covers sentinel row too) ----------------
__global__ __launch_bounds__(256) void dot_k(const unsigned short* __restrict__ hp2,
                                             const float* __restrict__ wtil,
                                             float* __restrict__ sp) {
    int t = blockIdx.x * 256 + threadIdx.x;
    int node = t >> 4;
    if (node > N_NODES) return;
    int sub = t & 15;
    uint4 v = ((const uint4*)hp2)[(size_t)node * 16 + sub];
    float4 wa = *(const float4*)(wtil + sub * 8);
    float4 wb = *(const float4*)(wtil + sub * 8 + 4);
    float p = bflo(v.x) * wa.x + bfhi(v.x) * wa.y + bflo(v.y) * wa.z + bfhi(v.y) * wa.w
            + bflo(v.z) * wb.x + bfhi(v.z) * wb.y + bflo(v.w) * wb.z + bfhi(v.w) * wb.w;
#pragma unroll
    for (int o = 8; o >= 1; o >>= 1) p += __shfl_xor(p, o, 64);
    if (sub == 0) sp[node] = p;
}

// ---------------- graph head: scalar layer-3 agg + mean + sigmoid ----------------
__global__ __launch_bounds__(256) void gout_k(const float* __restrict__ sp,
                                              const int* __restrict__ goff,
                                              const int* __restrict__ offs,
                                              const int* __restrict__ csrc,
                                              const float* __restrict__ dinv,
                                              const float* __restrict__ cbuf,
                                              const float* __restrict__ lin_b,
                                              float* __restrict__ out) {
    int wave = (blockIdx.x * 256 + threadIdx.x) >> 6;   // one wave per graph
    int lane = threadIdx.x & 63;
    if (wave >= N_GRAPHS) return;
    int s0 = goff[wave], s1 = goff[wave + 1];
    float s = 0.f;
    for (int j = s0 + lane; j < s1; j += 64) {
        int es = offs[j], ee = offs[j + 1];
        float acc = sp[j];                              // self
        for (int i = es; i < ee; i += 4) {
            int4 r = *(const int4*)(csrc + i);
            acc += sp[r.x] + sp[r.y] + sp[r.z] + sp[r.w];
        }
        s += dinv[j] * acc;
    }
#pragma unroll
    for (int o = 32; o >= 1; o >>= 1) s += __shfl_xor(s, o, 64);
    if (lane == 0) {
        int cnt = s1 - s0;
        float z = (cnt == 0) ? lin_b[0] : (s / (float)cnt + cbuf[0] + lin_b[0]);
        out[wave] = 1.0f / (1.0f + expf(-z));
    }
}

extern "C" void kernel_launch(void* const* d_in, const int* in_sizes, int n_in,
                              void* d_out, int out_size, void* d_ws, size_t ws_size,
                              hipStream_t stream) {
    const int* x      = (const int*)d_in[0];
    const int* ei     = (const int*)d_in[1];
    const int* batch  = (const int*)d_in[2];
    const float* emb  = (const float*)d_in[3];
    const float* W1   = (const float*)d_in[4];
    const float* b1   = (const float*)d_in[5];
    const float* W2   = (const float*)d_in[6];
    const float* b2   = (const float*)d_in[7];
    const float* W3   = (const float*)d_in[8];
    const float* b3   = (const float*)d_in[9];
    const float* lw   = (const float*)d_in[10];
    const float* lb   = (const float*)d_in[11];
    float* out = (float*)d_out;

    char* ws = (char*)d_ws;
    size_t off = 0;
    auto alloc = [&](size_t bytes) {
        void* p = ws + off;
        off = (off + bytes + 255) & ~(size_t)255;
        return p;
    };
    int*   deg     = (int*)alloc((size_t)N_NODES * 4);
    int*   cursor  = (int*)alloc((size_t)N_NODES * 4);
    float* dinv    = (float*)alloc((size_t)N_NODES * 4);
    int*   offs    = (int*)alloc((size_t)(N_NODES + 1) * 4);
    int*   bsum    = (int*)alloc((size_t)NB_SCAN * 4);
    int*   csrc    = (int*)alloc((size_t)CSR_CAP * 4);
    unsigned short* hpA = (unsigned short*)alloc((size_t)NPAD32 * HID * 2);
    unsigned short* hpB = (unsigned short*)alloc((size_t)NPAD32 * HID * 2);
    unsigned short* Wt  = (unsigned short*)alloc((size_t)2 * HID * HID * 2);
    float* wtil    = (float*)alloc((size_t)HID * 4);
    float* cbuf    = (float*)alloc(256);
    float* sp      = (float*)alloc((size_t)(N_NODES + 1) * 4);
    int*   goff    = (int*)alloc((size_t)(N_GRAPHS + 1) * 4);

    const int* row = ei;
    const int* col = ei + N_EDGES;

    init_k<<<NB_SCAN, 256, 0, stream>>>(deg, cursor,
                                        (unsigned int*)(hpA + (size_t)N_NODES * HID));
    count_k<<<(N_EDGES + 255) / 256, 256, 0, stream>>>(col, deg);
    scan1_k<<<NB_SCAN, 256, 0, stream>>>(deg, dinv, offs, bsum);
    scan2_k<<<1, 256, 0, stream>>>(bsum, offs);
    scan3pad_k<<<NB_SCAN, 256, 0, stream>>>(offs, bsum, deg, csrc);
    fill_k<<<(N_EDGES + 255) / 256, 256, 0, stream>>>(row, col, offs, cursor, csrc);
    prep_k<<<(32897 + N_NODES + 1 + 255) / 256, 256, 0, stream>>>(
        W1, W2, W3, b3, lw, batch, Wt, wtil, cbuf, goff);
    atom_k<<<(N_NODES * 32 + 255) / 256, 256, 0, stream>>>(x, emb, dinv, hpA);

    // layers 1,2: fused gather + MFMA
    fused_k<<<NPAD32 / 32, 256, 0, stream>>>(hpA, Wt, b1, dinv, offs, csrc, hpB);
    fused_k<<<NPAD32 / 32, 256, 0, stream>>>(hpB, Wt + 16384, b2, dinv, offs, csrc, hpA);

    // layer 3 collapsed to scalars: sp = hp2 . w~, then scalar agg in head
    dot_k<<<((N_NODES + 1) * 16 + 255) / 256, 256, 0, stream>>>(hpA, wtil, sp);
    gout_k<<<(N_GRAPHS * 64 + 255) / 256, 256, 0, stream>>>(sp, goff, offs, csrc,
                                                            dinv, cbuf, lb, out);
}

// Round 7
// 169.870 us; speedup vs baseline: 3.5281x; 1.1267x over previous
//
#include <hip/hip_runtime.h>
#include <hip/hip_bf16.h>
#include <math.h>

#define N_NODES 50000
#define N_EDGES 625000
#define HID 128
#define N_GRAPHS 1000
#define N_FEATS 9
#define VOCAB 119
#define SENTINEL N_NODES    // pad gathers hit this all-zero row
#define CSR_CAP (N_EDGES + 3 * N_NODES)   // segments padded to multiple of 4
#define NB_SCAN ((N_NODES + 255) / 256)   // 196 scan blocks
#define LDSW 136            // 128 + 8 pad shorts: keeps 16B align, breaks bank conflicts
#define NBLK (N_NODES / 16) // 3125 fused blocks, exact

typedef __attribute__((ext_vector_type(8))) short short8;
typedef __attribute__((ext_vector_type(4))) float f32x4;

// ---- bf16 helpers ----
static __device__ __forceinline__ float bflo(unsigned int w) {
    return __uint_as_float(w << 16);
}
static __device__ __forceinline__ float bfhi(unsigned int w) {
    return __uint_as_float(w & 0xffff0000u);
}
static __device__ __forceinline__ unsigned int f2bf(float f) {
    unsigned int u = __float_as_uint(f);
    return (u + 0x7fffu + ((u >> 16) & 1u)) >> 16;   // RNE
}
static __device__ __forceinline__ uint2 pack4(float a, float b, float c, float d) {
    uint2 r;
    r.x = f2bf(a) | (f2bf(b) << 16);
    r.y = f2bf(c) | (f2bf(d) << 16);
    return r;
}

// ---------------- init: zero deg/cursor + sentinel rows + sp sentinel ----------------
__global__ __launch_bounds__(256) void init_k(int* __restrict__ deg,
                                              int* __restrict__ cursor,
                                              unsigned int* __restrict__ hpA_sent,
                                              unsigned int* __restrict__ hpB_sent,
                                              float* __restrict__ sp) {
    int i = blockIdx.x * 256 + threadIdx.x;
    if (i < N_NODES) { deg[i] = 0; cursor[i] = 0; }
    if (i < 64) { hpA_sent[i] = 0; hpB_sent[i] = 0; }   // row 50000: 128 bf16 = 64 u32
    if (i == 64) sp[SENTINEL] = 0.f;
}

// ---------------- degree count ----------------
__global__ __launch_bounds__(256) void count_k(const int* __restrict__ col,
                                               int* __restrict__ deg) {
    int e = blockIdx.x * 256 + threadIdx.x;
    if (e >= N_EDGES) return;
    atomicAdd(&deg[col[e]], 1);
}

// ---------------- scan pass 1 over round4(deg); also computes dinv ----------------
__global__ __launch_bounds__(256) void scan1_k(const int* __restrict__ deg,
                                               float* __restrict__ dinv,
                                               int* __restrict__ offs,
                                               int* __restrict__ bsum) {
    __shared__ int sh[256];
    int i = blockIdx.x * 256 + threadIdx.x;
    int d = (i < N_NODES) ? deg[i] : 0;
    if (i < N_NODES) dinv[i] = rsqrtf((float)(d + 1));   // +1 self loop
    int v = (d + 3) & ~3;                                // padded segment length
    sh[threadIdx.x] = v;
    __syncthreads();
#pragma unroll
    for (int o = 1; o < 256; o <<= 1) {
        int t = (threadIdx.x >= o) ? sh[threadIdx.x - o] : 0;
        __syncthreads();
        sh[threadIdx.x] += t;
        __syncthreads();
    }
    if (i < N_NODES) offs[i] = sh[threadIdx.x] - v;
    if (threadIdx.x == 255) bsum[blockIdx.x] = sh[255];
}

__global__ __launch_bounds__(256) void scan2_k(int* __restrict__ bsum,
                                               int* __restrict__ offs) {
    __shared__ int sh[256];
    int v = (threadIdx.x < NB_SCAN) ? bsum[threadIdx.x] : 0;
    sh[threadIdx.x] = v;
    __syncthreads();
#pragma unroll
    for (int o = 1; o < 256; o <<= 1) {
        int t = (threadIdx.x >= o) ? sh[threadIdx.x - o] : 0;
        __syncthreads();
        sh[threadIdx.x] += t;
        __syncthreads();
    }
    if (threadIdx.x < NB_SCAN) bsum[threadIdx.x] = sh[threadIdx.x] - v;
    if (threadIdx.x == 255) offs[N_NODES] = sh[255];
}

// ---------------- scan3 + sentinel pad, merged ----------------
__global__ __launch_bounds__(256) void scan3pad_k(int* __restrict__ offs,
                                                  const int* __restrict__ bsum,
                                                  const int* __restrict__ deg,
                                                  int* __restrict__ csrc) {
    int i = blockIdx.x * 256 + threadIdx.x;
    if (i >= N_NODES) return;
    int o = offs[i] + bsum[blockIdx.x];
    offs[i] = o;
    int d = deg[i];
    int r4 = (d + 3) & ~3;
    for (int j = d; j < r4; j++) csrc[o + j] = SENTINEL;
}

// ---------------- CSR fill (indices only) ----------------
__global__ __launch_bounds__(256) void fill_k(const int* __restrict__ row,
                                              const int* __restrict__ col,
                                              const int* __restrict__ offs,
                                              int* __restrict__ cursor,
                                              int* __restrict__ csrc) {
    int e = blockIdx.x * 256 + threadIdx.x;
    if (e >= N_EDGES) return;
    int c = col[e];
    int pos = offs[c] + atomicAdd(&cursor[c], 1);
    csrc[pos] = row[e];
}

// ---------------- prep: Wt1/Wt2 transpose, w~ = W3@lin_w, cb3 = b3.lin_w, goff ----------------
__global__ __launch_bounds__(256) void prep_k(const float* __restrict__ W1,
                                              const float* __restrict__ W2,
                                              const float* __restrict__ W3,
                                              const float* __restrict__ b3,
                                              const float* __restrict__ lw,
                                              const int* __restrict__ batch,
                                              unsigned short* __restrict__ Wt,
                                              float* __restrict__ wtil,
                                              float* __restrict__ cbuf,
                                              int* __restrict__ goff) {
    int t = blockIdx.x * 256 + threadIdx.x;
    if (t < 32768) {                         // W^T for layers 1,2
        int which = t >> 14;
        int rem = t & 16383;
        int n = rem >> 7, k = rem & 127;
        const float* W = which ? W2 : W1;
        Wt[which * 16384 + n * 128 + k] = (unsigned short)f2bf(W[k * 128 + n]);
    } else if (t < 32896) {                  // w~[k] = sum_n W3[k][n]*lw[n]
        int k = t - 32768;
        float s = 0.f;
        for (int n = 0; n < 128; n++) s += W3[k * 128 + n] * lw[n];
        wtil[k] = s;
    } else if (t == 32896) {                 // cb3 = b3 . lw
        float s = 0.f;
        for (int n = 0; n < 128; n++) s += b3[n] * lw[n];
        cbuf[0] = s;
    } else {                                 // goff from sorted batch
        int i = t - 32897;
        if (i > N_NODES) return;
        int bprev = (i == 0) ? -1 : batch[i - 1];
        int bcur = (i == N_NODES) ? N_GRAPHS : batch[i];
        for (int g = bprev + 1; g <= bcur; g++) goff[g] = i;
    }
}

// ---------------- atom encoder -> prescaled bf16 hp0 = dinv*h0 ----------------
__global__ __launch_bounds__(256) void atom_k(const int* __restrict__ x,
                                              const float* __restrict__ emb,
                                              const float* __restrict__ dinv,
                                              unsigned short* __restrict__ hp) {
    int gid = blockIdx.x * 256 + threadIdx.x;   // N*32 threads
    int node = gid >> 5;
    int sub = gid & 31;
    if (node >= N_NODES) return;
    int d4 = sub * 4;
    float4 acc = make_float4(0.f, 0.f, 0.f, 0.f);
#pragma unroll
    for (int f = 0; f < N_FEATS; f++) {
        int idx = x[node * N_FEATS + f];
        const float4 v = *(const float4*)(emb + ((size_t)(f * VOCAB + idx)) * HID + d4);
        acc.x += v.x; acc.y += v.y; acc.z += v.z; acc.w += v.w;
    }
    float di = dinv[node];
    ((uint2*)hp)[(size_t)node * 32 + sub] =
        pack4(di * acc.x, di * acc.y, di * acc.z, di * acc.w);
}

// ---------------- fused layer: 16 nodes/block, one node per 16-lane group ----------------
// Phase 1: gather (A^ hp_in) rows into LDS bf16 tile [16][LDSW].
// Phase 2: 4 waves x (16 rows x 32 cols) MFMA vs Wt.
// DOT=0: write hp_out = dinv*relu(.+b). DOT=1: write sp = (dinv*relu(.+b)).wtil only.
template <int DOT>
__global__ __launch_bounds__(256) void fused_k(const unsigned short* __restrict__ hp_in,
                                               const unsigned short* __restrict__ Wt,
                                               const float* __restrict__ bias,
                                               const float* __restrict__ dinv,
                                               const int* __restrict__ offs,
                                               const int* __restrict__ csrc,
                                               unsigned short* __restrict__ hp_out,
                                               const float* __restrict__ wtil,
                                               float* __restrict__ sp) {
    __shared__ unsigned short a_sh[16 * LDSW];
    __shared__ float spart[64];
    int tid = threadIdx.x;
    int sub = tid & 15, nl = tid >> 4;          // nl = node_local 0..15
    int node = blockIdx.x * 16 + nl;            // always < N_NODES (50000 = 16*3125)
    const uint4* H = (const uint4*)hp_in;
    {
        int s = offs[node], e = offs[node + 1];
        uint4 v = H[(size_t)node * 16 + sub];   // self (prescaled)
        float a0 = bflo(v.x), a1 = bfhi(v.x), a2 = bflo(v.y), a3 = bfhi(v.y);
        float a4 = bflo(v.z), a5 = bfhi(v.z), a6 = bflo(v.w), a7 = bfhi(v.w);
        for (int i = s; i < e; i += 4) {
            int4 r = *(const int4*)(csrc + i);
            uint4 u0 = H[(size_t)r.x * 16 + sub];
            uint4 u1 = H[(size_t)r.y * 16 + sub];
            uint4 u2 = H[(size_t)r.z * 16 + sub];
            uint4 u3 = H[(size_t)r.w * 16 + sub];
            a0 += bflo(u0.x); a1 += bfhi(u0.x); a2 += bflo(u0.y); a3 += bfhi(u0.y);
            a4 += bflo(u0.z); a5 += bfhi(u0.z); a6 += bflo(u0.w); a7 += bfhi(u0.w);
            a0 += bflo(u1.x); a1 += bfhi(u1.x); a2 += bflo(u1.y); a3 += bfhi(u1.y);
            a4 += bflo(u1.z); a5 += bfhi(u1.z); a6 += bflo(u1.w); a7 += bfhi(u1.w);
            a0 += bflo(u2.x); a1 += bfhi(u2.x); a2 += bflo(u2.y); a3 += bfhi(u2.y);
            a4 += bflo(u2.z); a5 += bfhi(u2.z); a6 += bflo(u2.w); a7 += bfhi(u2.w);
            a0 += bflo(u3.x); a1 += bfhi(u3.x); a2 += bflo(u3.y); a3 += bfhi(u3.y);
            a4 += bflo(u3.z); a5 += bfhi(u3.z); a6 += bflo(u3.w); a7 += bfhi(u3.w);
        }
        float di = dinv[node];                  // (A^ h)_i = di * (sum + self)
        uint2 p0 = pack4(di * a0, di * a1, di * a2, di * a3);
        uint2 p1 = pack4(di * a4, di * a5, di * a6, di * a7);
        uint4 o; o.x = p0.x; o.y = p0.y; o.z = p1.x; o.w = p1.y;
        *(uint4*)(a_sh + nl * LDSW + sub * 8) = o;
    }
    __syncthreads();
    // MFMA phase: wave w -> cols w*32..+31, rows 0..15
    int w = tid >> 6, l = tid & 63;
    int lm = l & 15, lk = l >> 4;
    int cbase = w * 32;
    f32x4 acc[2];
    acc[0] = (f32x4)0.f; acc[1] = (f32x4)0.f;
#pragma unroll
    for (int kk = 0; kk < 4; kk++) {
        short8 af = *(const short8*)(a_sh + lm * LDSW + (kk * 4 + lk) * 8);
#pragma unroll
        for (int nt = 0; nt < 2; nt++) {
            short8 bf = *(const short8*)(Wt + (size_t)(cbase + nt * 16 + lm) * HID + (kk * 4 + lk) * 8);
            acc[nt] = __builtin_amdgcn_mfma_f32_16x16x32_bf16(bf, af, acc[nt], 0, 0, 0);
        }
    }
    int m = blockIdx.x * 16 + lm;
    float di = dinv[m];
    if (DOT == 0) {
#pragma unroll
        for (int nt = 0; nt < 2; nt++) {
            int n0 = cbase + nt * 16 + lk * 4;
            float4 b4 = *(const float4*)(bias + n0);
            float o0 = di * fmaxf(acc[nt][0] + b4.x, 0.f);
            float o1 = di * fmaxf(acc[nt][1] + b4.y, 0.f);
            float o2 = di * fmaxf(acc[nt][2] + b4.z, 0.f);
            float o3 = di * fmaxf(acc[nt][3] + b4.w, 0.f);
            *(uint2*)(hp_out + (size_t)m * HID + n0) = pack4(o0, o1, o2, o3);
        }
    } else {
        float s = 0.f;
#pragma unroll
        for (int nt = 0; nt < 2; nt++) {
            int n0 = cbase + nt * 16 + lk * 4;
            float4 b4 = *(const float4*)(bias + n0);
            float4 w4 = *(const float4*)(wtil + n0);
            s += di * fmaxf(acc[nt][0] + b4.x, 0.f) * w4.x
               + di * fmaxf(acc[nt][1] + b4.y, 0.f) * w4.y
               + di * fmaxf(acc[nt][2] + b4.z, 0.f) * w4.z
               + di * fmaxf(acc[nt][3] + b4.w, 0.f) * w4.w;
        }
        s += __shfl_xor(s, 16, 64);
        s += __shfl_xor(s, 32, 64);             // lanes with lk==0 hold row sum of 32 cols
        if (lk == 0) spart[w * 16 + lm] = s;
        __syncthreads();
        if (tid < 16)
            sp[blockIdx.x * 16 + tid] =
                spart[tid] + spart[16 + tid] + spart[32 + tid] + spart[48 + tid];
    }
}

// ---------------- graph head: scalar layer-3 agg + mean + sigmoid ----------------
__global__ __launch_bounds__(256) void gout_k(const float* __restrict__ sp,
                                              const int* __restrict__ goff,
                                              const int* __restrict__ offs,
                                              const int* __restrict__ csrc,
                                              const float* __restrict__ dinv,
                                              const float* __restrict__ cbuf,
                                              const float* __restrict__ lin_b,
                                              float* __restrict__ out) {
    int wave = (blockIdx.x * 256 + threadIdx.x) >> 6;   // one wave per graph
    int lane = threadIdx.x & 63;
    if (wave >= N_GRAPHS) return;
    int s0 = goff[wave], s1 = goff[wave + 1];
    float s = 0.f;
    for (int j = s0 + lane; j < s1; j += 64) {
        int es = offs[j], ee = offs[j + 1];
        float acc = sp[j];                              // self
        for (int i = es; i < ee; i += 4) {
            int4 r = *(const int4*)(csrc + i);
            acc += sp[r.x] + sp[r.y] + sp[r.z] + sp[r.w];
        }
        s += dinv[j] * acc;
    }
#pragma unroll
    for (int o = 32; o >= 1; o >>= 1) s += __shfl_xor(s, o, 64);
    if (lane == 0) {
        int cnt = s1 - s0;
        float z = (cnt == 0) ? lin_b[0] : (s / (float)cnt + cbuf[0] + lin_b[0]);
        out[wave] = 1.0f / (1.0f + expf(-z));
    }
}

extern "C" void kernel_launch(void* const* d_in, const int* in_sizes, int n_in,
                              void* d_out, int out_size, void* d_ws, size_t ws_size,
                              hipStream_t stream) {
    const int* x      = (const int*)d_in[0];
    const int* ei     = (const int*)d_in[1];
    const int* batch  = (const int*)d_in[2];
    const float* emb  = (const float*)d_in[3];
    const float* W1   = (const float*)d_in[4];
    const float* b1   = (const float*)d_in[5];
    const float* W2   = (const float*)d_in[6];
    const float* b2   = (const float*)d_in[7];
    const float* W3   = (const float*)d_in[8];
    const float* b3   = (const float*)d_in[9];
    const float* lw   = (const float*)d_in[10];
    const float* lb   = (const float*)d_in[11];
    float* out = (float*)d_out;

    char* ws = (char*)d_ws;
    size_t off = 0;
    auto alloc = [&](size_t bytes) {
        void* p = ws + off;
        off = (off + bytes + 255) & ~(size_t)255;
        return p;
    };
    int*   deg     = (int*)alloc((size_t)N_NODES * 4);
    int*   cursor  = (int*)alloc((size_t)N_NODES * 4);
    float* dinv    = (float*)alloc((size_t)N_NODES * 4);
    int*   offs    = (int*)alloc((size_t)(N_NODES + 1) * 4);
    int*   bsum    = (int*)alloc((size_t)NB_SCAN * 4);
    int*   csrc    = (int*)alloc((size_t)CSR_CAP * 4);
    unsigned short* hpA = (unsigned short*)alloc((size_t)(N_NODES + 1) * HID * 2);
    unsigned short* hpB = (unsigned short*)alloc((size_t)(N_NODES + 1) * HID * 2);
    unsigned short* Wt  = (unsigned short*)alloc((size_t)2 * HID * HID * 2);
    float* wtil    = (float*)alloc((size_t)HID * 4);
    float* cbuf    = (float*)alloc(256);
    float* sp      = (float*)alloc((size_t)(N_NODES + 1) * 4);
    int*   goff    = (int*)alloc((size_t)(N_GRAPHS + 1) * 4);

    const int* row = ei;
    const int* col = ei + N_EDGES;

    init_k<<<NB_SCAN, 256, 0, stream>>>(deg, cursor,
                                        (unsigned int*)(hpA + (size_t)SENTINEL * HID),
                                        (unsigned int*)(hpB + (size_t)SENTINEL * HID),
                                        sp);
    count_k<<<(N_EDGES + 255) / 256, 256, 0, stream>>>(col, deg);
    scan1_k<<<NB_SCAN, 256, 0, stream>>>(deg, dinv, offs, bsum);
    scan2_k<<<1, 256, 0, stream>>>(bsum, offs);
    scan3pad_k<<<NB_SCAN, 256, 0, stream>>>(offs, bsum, deg, csrc);
    fill_k<<<(N_EDGES + 255) / 256, 256, 0, stream>>>(row, col, offs, cursor, csrc);
    prep_k<<<(32897 + N_NODES + 1 + 255) / 256, 256, 0, stream>>>(
        W1, W2, W3, b3, lw, batch, Wt, wtil, cbuf, goff);
    atom_k<<<(N_NODES * 32 + 255) / 256, 256, 0, stream>>>(x, emb, dinv, hpA);

    // layer 1: fused gather + MFMA -> hpB
    fused_k<0><<<NBLK, 256, 0, stream>>>(hpA, Wt, b1, dinv, offs, csrc, hpB, wtil, sp);
    // layer 2: fused gather + MFMA + dot(w~) -> sp directly (no hp write)
    fused_k<1><<<NBLK, 256, 0, stream>>>(hpB, Wt + 16384, b2, dinv, offs, csrc, hpA, wtil, sp);

    // head: scalar layer-3 agg + mean + sigmoid
    gout_k<<<(N_GRAPHS * 64 + 255) / 256, 256, 0, stream>>>(sp, goff, offs, csrc,
                                                            dinv, cbuf, lb, out);
}

// Round 8
// 158.174 us; speedup vs baseline: 3.7890x; 1.0739x over previous
//
#include <hip/hip_runtime.h>
#include <hip/hip_bf16.h>
#include <math.h>

#define N_NODES 50000
#define N_EDGES 625000
#define HID 128
#define N_GRAPHS 1000
#define N_FEATS 9
#define VOCAB 119
#define SENTINEL N_NODES    // pad gathers hit this all-zero row
#define CSR_CAP (N_EDGES + 3 * N_NODES)   // segments padded to multiple of 4
#define NB_SCAN ((N_NODES + 255) / 256)   // 196 scan blocks
#define LDSW 136            // 128 + 8 pad shorts: keeps 16B align, breaks bank conflicts
#define NBLK (N_NODES / 16) // 3125 fused blocks, exact

// fat mid_k block ranges
#define FB ((N_EDGES + 255) / 256)            // 2442 fill blocks
#define PB ((32897 + N_NODES + 1 + 255) / 256) // 325 prep blocks
#define AB ((N_NODES * 32) / 256)             // 6250 atom blocks

typedef __attribute__((ext_vector_type(8))) short short8;
typedef __attribute__((ext_vector_type(4))) float f32x4;

// ---- bf16 helpers ----
static __device__ __forceinline__ float bflo(unsigned int w) {
    return __uint_as_float(w << 16);
}
static __device__ __forceinline__ float bfhi(unsigned int w) {
    return __uint_as_float(w & 0xffff0000u);
}
static __device__ __forceinline__ unsigned int f2bf(float f) {
    unsigned int u = __float_as_uint(f);
    return (u + 0x7fffu + ((u >> 16) & 1u)) >> 16;   // RNE
}
static __device__ __forceinline__ uint2 pack4(float a, float b, float c, float d) {
    uint2 r;
    r.x = f2bf(a) | (f2bf(b) << 16);
    r.y = f2bf(c) | (f2bf(d) << 16);
    return r;
}

// ---------------- init: zero deg + sentinel rows + sp sentinel ----------------
__global__ __launch_bounds__(256) void init_k(int* __restrict__ deg,
                                              unsigned int* __restrict__ hpA_sent,
                                              unsigned int* __restrict__ hpB_sent,
                                              float* __restrict__ sp) {
    int i = blockIdx.x * 256 + threadIdx.x;
    if (i < N_NODES) deg[i] = 0;
    if (i < 64) { hpA_sent[i] = 0; hpB_sent[i] = 0; }   // row 50000: 128 bf16 = 64 u32
    if (i == 64) sp[SENTINEL] = 0.f;
}

// ---------------- degree count ----------------
__global__ __launch_bounds__(256) void count_k(const int* __restrict__ col,
                                               int* __restrict__ deg) {
    int e = blockIdx.x * 256 + threadIdx.x;
    if (e >= N_EDGES) return;
    atomicAdd(&deg[col[e]], 1);
}

// ---------------- scan pass 1 over round4(deg); also computes dinv ----------------
__global__ __launch_bounds__(256) void scan1_k(const int* __restrict__ deg,
                                               float* __restrict__ dinv,
                                               int* __restrict__ offs,
                                               int* __restrict__ bsum) {
    __shared__ int sh[256];
    int i = blockIdx.x * 256 + threadIdx.x;
    int d = (i < N_NODES) ? deg[i] : 0;
    if (i < N_NODES) dinv[i] = rsqrtf((float)(d + 1));   // +1 self loop
    int v = (d + 3) & ~3;                                // padded segment length
    sh[threadIdx.x] = v;
    __syncthreads();
#pragma unroll
    for (int o = 1; o < 256; o <<= 1) {
        int t = (threadIdx.x >= o) ? sh[threadIdx.x - o] : 0;
        __syncthreads();
        sh[threadIdx.x] += t;
        __syncthreads();
    }
    if (i < N_NODES) offs[i] = sh[threadIdx.x] - v;
    if (threadIdx.x == 255) bsum[blockIdx.x] = sh[255];
}

__global__ __launch_bounds__(256) void scan2_k(int* __restrict__ bsum,
                                               int* __restrict__ offs) {
    __shared__ int sh[256];
    int v = (threadIdx.x < NB_SCAN) ? bsum[threadIdx.x] : 0;
    sh[threadIdx.x] = v;
    __syncthreads();
#pragma unroll
    for (int o = 1; o < 256; o <<= 1) {
        int t = (threadIdx.x >= o) ? sh[threadIdx.x - o] : 0;
        __syncthreads();
        sh[threadIdx.x] += t;
        __syncthreads();
    }
    if (threadIdx.x < NB_SCAN) bsum[threadIdx.x] = sh[threadIdx.x] - v;
    if (threadIdx.x == 255) offs[N_NODES] = sh[255];
}

// ------- scan3 + sentinel pad + cursor preset (cursor[i] = offs[i]) -------
__global__ __launch_bounds__(256) void scan3pad_k(int* __restrict__ offs,
                                                  const int* __restrict__ bsum,
                                                  const int* __restrict__ deg,
                                                  int* __restrict__ cursor,
                                                  unsigned short* __restrict__ csrc) {
    int i = blockIdx.x * 256 + threadIdx.x;
    if (i >= N_NODES) return;
    int o = offs[i] + bsum[blockIdx.x];
    offs[i] = o;
    cursor[i] = o;                       // fill's atomicAdd returns final position
    int d = deg[i];
    int r4 = (d + 3) & ~3;
    for (int j = d; j < r4; j++) csrc[o + j] = (unsigned short)SENTINEL;
}

// ---------------- fat mid kernel: fill | prep | atom (independent work) ----------------
__global__ __launch_bounds__(256) void mid_k(const int* __restrict__ row,
                                             const int* __restrict__ col,
                                             int* __restrict__ cursor,
                                             unsigned short* __restrict__ csrc,
                                             const float* __restrict__ W1,
                                             const float* __restrict__ W2,
                                             const float* __restrict__ W3,
                                             const float* __restrict__ b3,
                                             const float* __restrict__ lw,
                                             const int* __restrict__ batch,
                                             unsigned short* __restrict__ Wt,
                                             float* __restrict__ wtil,
                                             float* __restrict__ cbuf,
                                             int* __restrict__ goff,
                                             const int* __restrict__ x,
                                             const float* __restrict__ emb,
                                             const float* __restrict__ dinv,
                                             unsigned short* __restrict__ hp) {
    int b = blockIdx.x;
    if (b < FB) {
        // ---- CSR fill: cursor preloaded with offs, single atomic gives position ----
        int e = b * 256 + threadIdx.x;
        if (e >= N_EDGES) return;
        int c = col[e];
        int pos = atomicAdd(&cursor[c], 1);
        csrc[pos] = (unsigned short)row[e];
    } else if (b < FB + PB) {
        // ---- prep: Wt transpose, w~, cb3, goff ----
        int t = (b - FB) * 256 + threadIdx.x;
        if (t < 32768) {
            int which = t >> 14;
            int rem = t & 16383;
            int n = rem >> 7, k = rem & 127;
            const float* W = which ? W2 : W1;
            Wt[which * 16384 + n * 128 + k] = (unsigned short)f2bf(W[k * 128 + n]);
        } else if (t < 32896) {
            int k = t - 32768;
            float s = 0.f;
            for (int n = 0; n < 128; n++) s += W3[k * 128 + n] * lw[n];
            wtil[k] = s;
        } else if (t == 32896) {
            float s = 0.f;
            for (int n = 0; n < 128; n++) s += b3[n] * lw[n];
            cbuf[0] = s;
        } else {
            int i = t - 32897;
            if (i > N_NODES) return;
            int bprev = (i == 0) ? -1 : batch[i - 1];
            int bcur = (i == N_NODES) ? N_GRAPHS : batch[i];
            for (int g = bprev + 1; g <= bcur; g++) goff[g] = i;
        }
    } else {
        // ---- atom encoder -> prescaled bf16 hp0 = dinv*h0 ----
        int gid = (b - FB - PB) * 256 + threadIdx.x;
        int node = gid >> 5;
        int sub = gid & 31;
        if (node >= N_NODES) return;
        int d4 = sub * 4;
        float4 acc = make_float4(0.f, 0.f, 0.f, 0.f);
#pragma unroll
        for (int f = 0; f < N_FEATS; f++) {
            int idx = x[node * N_FEATS + f];
            const float4 v = *(const float4*)(emb + ((size_t)(f * VOCAB + idx)) * HID + d4);
            acc.x += v.x; acc.y += v.y; acc.z += v.z; acc.w += v.w;
        }
        float di = dinv[node];
        ((uint2*)hp)[(size_t)node * 32 + sub] =
            pack4(di * acc.x, di * acc.y, di * acc.z, di * acc.w);
    }
}

// ---------------- fused layer: 16 nodes/block, one node per 16-lane group ----------------
template <int DOT>
__global__ __launch_bounds__(256) void fused_k(const unsigned short* __restrict__ hp_in,
                                               const unsigned short* __restrict__ Wt,
                                               const float* __restrict__ bias,
                                               const float* __restrict__ dinv,
                                               const int* __restrict__ offs,
                                               const unsigned short* __restrict__ csrc,
                                               unsigned short* __restrict__ hp_out,
                                               const float* __restrict__ wtil,
                                               float* __restrict__ sp) {
    __shared__ unsigned short a_sh[16 * LDSW];
    __shared__ float spart[64];
    int tid = threadIdx.x;
    int sub = tid & 15, nl = tid >> 4;          // nl = node_local 0..15
    int node = blockIdx.x * 16 + nl;            // always < N_NODES (50000 = 16*3125)
    const uint4* H = (const uint4*)hp_in;
    {
        int s = offs[node], e = offs[node + 1];
        uint4 v = H[(size_t)node * 16 + sub];   // self (prescaled)
        float a0 = bflo(v.x), a1 = bfhi(v.x), a2 = bflo(v.y), a3 = bfhi(v.y);
        float a4 = bflo(v.z), a5 = bfhi(v.z), a6 = bflo(v.w), a7 = bfhi(v.w);
        for (int i = s; i < e; i += 4) {
            ushort4 r = *(const ushort4*)(csrc + i);   // 8B aligned (segments %4)
            uint4 u0 = H[(size_t)r.x * 16 + sub];
            uint4 u1 = H[(size_t)r.y * 16 + sub];
            uint4 u2 = H[(size_t)r.z * 16 + sub];
            uint4 u3 = H[(size_t)r.w * 16 + sub];
            a0 += bflo(u0.x); a1 += bfhi(u0.x); a2 += bflo(u0.y); a3 += bfhi(u0.y);
            a4 += bflo(u0.z); a5 += bfhi(u0.z); a6 += bflo(u0.w); a7 += bfhi(u0.w);
            a0 += bflo(u1.x); a1 += bfhi(u1.x); a2 += bflo(u1.y); a3 += bfhi(u1.y);
            a4 += bflo(u1.z); a5 += bfhi(u1.z); a6 += bflo(u1.w); a7 += bfhi(u1.w);
            a0 += bflo(u2.x); a1 += bfhi(u2.x); a2 += bflo(u2.y); a3 += bfhi(u2.y);
            a4 += bflo(u2.z); a5 += bfhi(u2.z); a6 += bflo(u2.w); a7 += bfhi(u2.w);
            a0 += bflo(u3.x); a1 += bfhi(u3.x); a2 += bflo(u3.y); a3 += bfhi(u3.y);
            a4 += bflo(u3.z); a5 += bfhi(u3.z); a6 += bflo(u3.w); a7 += bfhi(u3.w);
        }
        float di = dinv[node];                  // (A^ h)_i = di * (sum + self)
        uint2 p0 = pack4(di * a0, di * a1, di * a2, di * a3);
        uint2 p1 = pack4(di * a4, di * a5, di * a6, di * a7);
        uint4 o; o.x = p0.x; o.y = p0.y; o.z = p1.x; o.w = p1.y;
        *(uint4*)(a_sh + nl * LDSW + sub * 8) = o;
    }
    __syncthreads();
    // MFMA phase: wave w -> cols w*32..+31, rows 0..15
    int w = tid >> 6, l = tid & 63;
    int lm = l & 15, lk = l >> 4;
    int cbase = w * 32;
    f32x4 acc[2];
    acc[0] = (f32x4)0.f; acc[1] = (f32x4)0.f;
#pragma unroll
    for (int kk = 0; kk < 4; kk++) {
        short8 af = *(const short8*)(a_sh + lm * LDSW + (kk * 4 + lk) * 8);
#pragma unroll
        for (int nt = 0; nt < 2; nt++) {
            short8 bf = *(const short8*)(Wt + (size_t)(cbase + nt * 16 + lm) * HID + (kk * 4 + lk) * 8);
            acc[nt] = __builtin_amdgcn_mfma_f32_16x16x32_bf16(bf, af, acc[nt], 0, 0, 0);
        }
    }
    int m = blockIdx.x * 16 + lm;
    float di = dinv[m];
    if (DOT == 0) {
#pragma unroll
        for (int nt = 0; nt < 2; nt++) {
            int n0 = cbase + nt * 16 + lk * 4;
            float4 b4 = *(const float4*)(bias + n0);
            float o0 = di * fmaxf(acc[nt][0] + b4.x, 0.f);
            float o1 = di * fmaxf(acc[nt][1] + b4.y, 0.f);
            float o2 = di * fmaxf(acc[nt][2] + b4.z, 0.f);
            float o3 = di * fmaxf(acc[nt][3] + b4.w, 0.f);
            *(uint2*)(hp_out + (size_t)m * HID + n0) = pack4(o0, o1, o2, o3);
        }
    } else {
        float s = 0.f;
#pragma unroll
        for (int nt = 0; nt < 2; nt++) {
            int n0 = cbase + nt * 16 + lk * 4;
            float4 b4 = *(const float4*)(bias + n0);
            float4 w4 = *(const float4*)(wtil + n0);
            s += di * fmaxf(acc[nt][0] + b4.x, 0.f) * w4.x
               + di * fmaxf(acc[nt][1] + b4.y, 0.f) * w4.y
               + di * fmaxf(acc[nt][2] + b4.z, 0.f) * w4.z
               + di * fmaxf(acc[nt][3] + b4.w, 0.f) * w4.w;
        }
        s += __shfl_xor(s, 16, 64);
        s += __shfl_xor(s, 32, 64);             // lanes with lk==0 hold row sum of 32 cols
        if (lk == 0) spart[w * 16 + lm] = s;
        __syncthreads();
        if (tid < 16)
            sp[blockIdx.x * 16 + tid] =
                spart[tid] + spart[16 + tid] + spart[32 + tid] + spart[48 + tid];
    }
}

// ---------------- graph head: scalar layer-3 agg + mean + sigmoid ----------------
__global__ __launch_bounds__(256) void gout_k(const float* __restrict__ sp,
                                              const int* __restrict__ goff,
                                              const int* __restrict__ offs,
                                              const unsigned short* __restrict__ csrc,
                                              const float* __restrict__ dinv,
                                              const float* __restrict__ cbuf,
                                              const float* __restrict__ lin_b,
                                              float* __restrict__ out) {
    int wave = (blockIdx.x * 256 + threadIdx.x) >> 6;   // one wave per graph
    int lane = threadIdx.x & 63;
    if (wave >= N_GRAPHS) return;
    int s0 = goff[wave], s1 = goff[wave + 1];
    float s = 0.f;
    for (int j = s0 + lane; j < s1; j += 64) {
        int es = offs[j], ee = offs[j + 1];
        float acc = sp[j];                              // self
        for (int i = es; i < ee; i += 4) {
            ushort4 r = *(const ushort4*)(csrc + i);
            acc += sp[r.x] + sp[r.y] + sp[r.z] + sp[r.w];
        }
        s += dinv[j] * acc;
    }
#pragma unroll
    for (int o = 32; o >= 1; o >>= 1) s += __shfl_xor(s, o, 64);
    if (lane == 0) {
        int cnt = s1 - s0;
        float z = (cnt == 0) ? lin_b[0] : (s / (float)cnt + cbuf[0] + lin_b[0]);
        out[wave] = 1.0f / (1.0f + expf(-z));
    }
}

extern "C" void kernel_launch(void* const* d_in, const int* in_sizes, int n_in,
                              void* d_out, int out_size, void* d_ws, size_t ws_size,
                              hipStream_t stream) {
    const int* x      = (const int*)d_in[0];
    const int* ei     = (const int*)d_in[1];
    const int* batch  = (const int*)d_in[2];
    const float* emb  = (const float*)d_in[3];
    const float* W1   = (const float*)d_in[4];
    const float* b1   = (const float*)d_in[5];
    const float* W2   = (const float*)d_in[6];
    const float* b2   = (const float*)d_in[7];
    const float* W3   = (const float*)d_in[8];
    const float* b3   = (const float*)d_in[9];
    const float* lw   = (const float*)d_in[10];
    const float* lb   = (const float*)d_in[11];
    float* out = (float*)d_out;

    char* ws = (char*)d_ws;
    size_t off = 0;
    auto alloc = [&](size_t bytes) {
        void* p = ws + off;
        off = (off + bytes + 255) & ~(size_t)255;
        return p;
    };
    int*   deg     = (int*)alloc((size_t)N_NODES * 4);
    int*   cursor  = (int*)alloc((size_t)N_NODES * 4);
    float* dinv    = (float*)alloc((size_t)N_NODES * 4);
    int*   offs    = (int*)alloc((size_t)(N_NODES + 1) * 4);
    int*   bsum    = (int*)alloc((size_t)NB_SCAN * 4);
    unsigned short* csrc = (unsigned short*)alloc((size_t)CSR_CAP * 2);
    unsigned short* hpA  = (unsigned short*)alloc((size_t)(N_NODES + 1) * HID * 2);
    unsigned short* hpB  = (unsigned short*)alloc((size_t)(N_NODES + 1) * HID * 2);
    unsigned short* Wt   = (unsigned short*)alloc((size_t)2 * HID * HID * 2);
    float* wtil    = (float*)alloc((size_t)HID * 4);
    float* cbuf    = (float*)alloc(256);
    float* sp      = (float*)alloc((size_t)(N_NODES + 1) * 4);
    int*   goff    = (int*)alloc((size_t)(N_GRAPHS + 1) * 4);

    const int* row = ei;
    const int* col = ei + N_EDGES;

    init_k<<<NB_SCAN, 256, 0, stream>>>(deg,
                                        (unsigned int*)(hpA + (size_t)SENTINEL * HID),
                                        (unsigned int*)(hpB + (size_t)SENTINEL * HID),
                                        sp);
    count_k<<<FB, 256, 0, stream>>>(col, deg);
    scan1_k<<<NB_SCAN, 256, 0, stream>>>(deg, dinv, offs, bsum);
    scan2_k<<<1, 256, 0, stream>>>(bsum, offs);
    scan3pad_k<<<NB_SCAN, 256, 0, stream>>>(offs, bsum, deg, cursor, csrc);
    // fat kernel: CSR fill | weight prep | atom encoder (all independent)
    mid_k<<<FB + PB + AB, 256, 0, stream>>>(row, col, cursor, csrc,
                                            W1, W2, W3, b3, lw, batch,
                                            Wt, wtil, cbuf, goff,
                                            x, emb, dinv, hpA);

    // layer 1: fused gather + MFMA -> hpB
    fused_k<0><<<NBLK, 256, 0, stream>>>(hpA, Wt, b1, dinv, offs, csrc, hpB, wtil, sp);
    // layer 2: fused gather + MFMA + dot(w~) -> sp directly (no hp write)
    fused_k<1><<<NBLK, 256, 0, stream>>>(hpB, Wt + 16384, b2, dinv, offs, csrc, hpA, wtil, sp);

    // head: scalar layer-3 agg + mean + sigmoid
    gout_k<<<(N_GRAPHS * 64 + 255) / 256, 256, 0, stream>>>(sp, goff, offs, csrc,
                                                            dinv, cbuf, lb, out);
}